// Round 1
// baseline (179.473 us; speedup 1.0000x reference)
//
#include <hip/hip_runtime.h>

#define S 2048
#define D 512
#define NH 32
#define DHD 16
#define DFF 1024
#define EPS 1e-5f

typedef unsigned short u16;
typedef __attribute__((ext_vector_type(8))) short short8;
typedef __attribute__((ext_vector_type(4))) float f32x4;
typedef __attribute__((ext_vector_type(4))) unsigned short us4;

static __device__ __forceinline__ u16 f2bf(float f) {
  union { float f; unsigned int i; } c; c.f = f;
  unsigned int x = c.i;
  return (u16)((x + 0x7fffu + ((x >> 16) & 1u)) >> 16);
}

static __device__ __forceinline__ void block_reduce2(float& a, float& b, float* sm, int t) {
#pragma unroll
  for (int m = 1; m <= 32; m <<= 1) {
    a += __shfl_xor(a, m);
    b += __shfl_xor(b, m);
  }
  int w = t >> 6;
  if ((t & 63) == 0) { sm[w] = a; sm[4 + w] = b; }
  __syncthreads();
  a = sm[0] + sm[1] + sm[2] + sm[3];
  b = sm[4] + sm[5] + sm[6] + sm[7];
  __syncthreads();
}

// ---------------- LN kernels ----------------
// ln0: x -> xn (fp32) and per-branch LN(xn)*g+b -> qin/kin/vin (bf16)
__global__ __launch_bounds__(256) void ln0_kernel(
    const float* __restrict__ x,
    const float* __restrict__ g0, const float* __restrict__ b0,
    const float* __restrict__ gq, const float* __restrict__ bq,
    const float* __restrict__ gk, const float* __restrict__ bk,
    const float* __restrict__ gv, const float* __restrict__ bv,
    float* __restrict__ xn, u16* __restrict__ qin, u16* __restrict__ kin,
    u16* __restrict__ vin) {
  __shared__ float red[8];
  int row = blockIdx.x, t = threadIdx.x;
  const float* xr = x + (size_t)row * D;
  float a0 = xr[t], a1 = xr[t + 256];
  float s = a0 + a1, ss = a0 * a0 + a1 * a1;
  block_reduce2(s, ss, red, t);
  float mean = s * (1.0f / D);
  float var = ss * (1.0f / D) - mean * mean;
  float rs = rsqrtf(var + EPS);
  float y0 = (a0 - mean) * rs * g0[t] + b0[t];
  float y1 = (a1 - mean) * rs * g0[t + 256] + b0[t + 256];
  size_t o = (size_t)row * D + t;
  xn[o] = y0;
  xn[o + 256] = y1;
  float s2 = y0 + y1, ss2 = y0 * y0 + y1 * y1;
  block_reduce2(s2, ss2, red, t);
  float m2 = s2 * (1.0f / D);
  float v2 = ss2 * (1.0f / D) - m2 * m2;
  float rs2 = rsqrtf(v2 + EPS);
  float c0 = (y0 - m2) * rs2, c1 = (y1 - m2) * rs2;
  qin[o] = f2bf(c0 * gq[t] + bq[t]);
  qin[o + 256] = f2bf(c1 * gq[t + 256] + bq[t + 256]);
  kin[o] = f2bf(c0 * gk[t] + bk[t]);
  kin[o + 256] = f2bf(c1 * gk[t + 256] + bk[t + 256]);
  vin[o] = f2bf(c0 * gv[t] + bv[t]);
  vin[o + 256] = f2bf(c1 * gv[t + 256] + bv[t + 256]);
}

__global__ __launch_bounds__(256) void ln2_kernel(
    const float* __restrict__ in, const float* __restrict__ g,
    const float* __restrict__ b, u16* __restrict__ out) {
  __shared__ float red[8];
  int row = blockIdx.x, t = threadIdx.x;
  const float* xr = in + (size_t)row * D;
  float a0 = xr[t], a1 = xr[t + 256];
  float s = a0 + a1, ss = a0 * a0 + a1 * a1;
  block_reduce2(s, ss, red, t);
  float mean = s * (1.0f / D);
  float var = ss * (1.0f / D) - mean * mean;
  float rs = rsqrtf(var + EPS);
  size_t o = (size_t)row * D + t;
  out[o] = f2bf((a0 - mean) * rs * g[t] + b[t]);
  out[o + 256] = f2bf((a1 - mean) * rs * g[t + 256] + b[t + 256]);
}

// ---------------- weight transpose fp32 -> bf16 ----------------
// W[K][N] -> Wt[N][K] (bf16)
__global__ void transpose_bf16(const float* __restrict__ W, u16* __restrict__ Wt,
                               int K, int N) {
  __shared__ float tile[32][33];
  int n0 = blockIdx.x * 32, k0 = blockIdx.y * 32;
  int tx = threadIdx.x, ty = threadIdx.y;  // (32,8)
#pragma unroll
  for (int i = 0; i < 4; ++i)
    tile[ty + 8 * i][tx] = W[(size_t)(k0 + ty + 8 * i) * N + n0 + tx];
  __syncthreads();
#pragma unroll
  for (int i = 0; i < 4; ++i)
    Wt[(size_t)(n0 + ty + 8 * i) * K + k0 + tx] = f2bf(tile[tx][ty + 8 * i]);
}

// ---------------- GEMM: C[M,N] = A[M,K](bf16) @ Bt[N,K]^T + bias ----------------
template <bool RELU, bool RESID, bool OUTBF>
__global__ __launch_bounds__(256) void gemm_kernel(
    const u16* __restrict__ A, const u16* __restrict__ Bt,
    const float* __restrict__ bias, const float* __restrict__ resid,
    float* __restrict__ outf, u16* __restrict__ outb, int M, int N, int K) {
  __shared__ u16 As[64][40];
  __shared__ u16 Bs[64][40];
  int t = threadIdx.x;
  int m0 = blockIdx.x * 64, n0 = blockIdx.y * 64;
  int wid = t >> 6, lane = t & 63;
  int wm = wid >> 1, wn = wid & 1;
  int lrow = t >> 2, lcol = (t & 3) * 8;
  int g = lane >> 4, lr = lane & 15;
  f32x4 acc[2][2] = {};
  for (int kk = 0; kk < K; kk += 32) {
    uint4 av = *(const uint4*)(A + (size_t)(m0 + lrow) * K + kk + lcol);
    uint4 bv = *(const uint4*)(Bt + (size_t)(n0 + lrow) * K + kk + lcol);
    *(uint4*)&As[lrow][lcol] = av;
    *(uint4*)&Bs[lrow][lcol] = bv;
    __syncthreads();
    short8 af[2], bfm[2];
    af[0] = *(const short8*)&As[wm * 32 + lr][g * 8];
    af[1] = *(const short8*)&As[wm * 32 + 16 + lr][g * 8];
    bfm[0] = *(const short8*)&Bs[wn * 32 + lr][g * 8];
    bfm[1] = *(const short8*)&Bs[wn * 32 + 16 + lr][g * 8];
#pragma unroll
    for (int mi = 0; mi < 2; ++mi)
#pragma unroll
      for (int ni = 0; ni < 2; ++ni)
        acc[mi][ni] = __builtin_amdgcn_mfma_f32_16x16x32_bf16(
            af[mi], bfm[ni], acc[mi][ni], 0, 0, 0);
    __syncthreads();
  }
#pragma unroll
  for (int mi = 0; mi < 2; ++mi)
#pragma unroll
    for (int ni = 0; ni < 2; ++ni)
#pragma unroll
      for (int r = 0; r < 4; ++r) {
        int row = m0 + wm * 32 + mi * 16 + g * 4 + r;
        int col = n0 + wn * 32 + ni * 16 + lr;
        float v = acc[mi][ni][r] + bias[col];
        if (RELU) v = fmaxf(v, 0.0f);
        if (RESID) v += resid[(size_t)row * N + col];
        if (OUTBF)
          outb[(size_t)row * N + col] = f2bf(v);
        else
          outf[(size_t)row * N + col] = v;
      }
}

// ---------------- causal flash attention ----------------
// Q/K/V: [S][D] bf16, head h occupies cols [h*16, h*16+16). ctx same layout.
__global__ __launch_bounds__(256) void attn_kernel(const u16* __restrict__ Qb,
                                                   const u16* __restrict__ Kb,
                                                   const u16* __restrict__ Vb,
                                                   u16* __restrict__ ctx) {
  __shared__ u16 Ks[64][24];
  __shared__ u16 Vt[16][72];
  __shared__ u16 Ps[4][16][72];
  int t = threadIdx.x, w = t >> 6, lane = t & 63;
  int h = blockIdx.y, q0 = blockIdx.x * 64;
  int qw = q0 + w * 16;
  int g = lane >> 4, lr = lane & 15;

  short8 qf = {};
  if (lane < 32)
    qf = *(const short8*)(Qb + (size_t)(qw + lr) * D + h * DHD + g * 8);

  f32x4 acc = {};
  float mrun[4], lrun[4];
#pragma unroll
  for (int r = 0; r < 4; ++r) { mrun[r] = -__builtin_inff(); lrun[r] = 0.0f; }

  int tmax = blockIdx.x;
  for (int tt = 0; tt <= tmax; ++tt) {
    int kv0 = tt * 64;
    {
      int i = t >> 2, d4 = (t & 3) * 4;
      us4 kvv = *(const us4*)(Kb + (size_t)(kv0 + i) * D + h * DHD + d4);
      *(us4*)&Ks[i][d4] = kvv;
      us4 vvv = *(const us4*)(Vb + (size_t)(kv0 + i) * D + h * DHD + d4);
#pragma unroll
      for (int j = 0; j < 4; ++j) Vt[d4 + j][i] = vvv[j];
    }
    __syncthreads();
    bool diag = (tt == tmax);

    f32x4 sfr[4];
#pragma unroll
    for (int kt = 0; kt < 4; ++kt) {
      short8 kf = {};
      if (lane < 32) kf = *(const short8*)&Ks[kt * 16 + lr][g * 8];
      f32x4 z = {};
      sfr[kt] = __builtin_amdgcn_mfma_f32_16x16x32_bf16(qf, kf, z, 0, 0, 0);
    }

    float sval[4][4];
#pragma unroll
    for (int kt = 0; kt < 4; ++kt)
#pragma unroll
      for (int r = 0; r < 4; ++r) {
        float sv = sfr[kt][r] * 0.25f;
        if (diag && (kv0 + kt * 16 + lr) > (qw + g * 4 + r)) sv = -1e30f;
        sval[kt][r] = sv;
      }

#pragma unroll
    for (int r = 0; r < 4; ++r) {
      float mx = fmaxf(fmaxf(sval[0][r], sval[1][r]), fmaxf(sval[2][r], sval[3][r]));
#pragma unroll
      for (int msk = 1; msk < 16; msk <<= 1) mx = fmaxf(mx, __shfl_xor(mx, msk));
      float mn = fmaxf(mrun[r], mx);
      float scr = __expf(mrun[r] - mn);
      float rowsum = 0.0f;
#pragma unroll
      for (int kt = 0; kt < 4; ++kt) {
        float pv = __expf(sval[kt][r] - mn);
        sval[kt][r] = pv;
        rowsum += pv;
      }
#pragma unroll
      for (int msk = 1; msk < 16; msk <<= 1) rowsum += __shfl_xor(rowsum, msk);
      lrun[r] = lrun[r] * scr + rowsum;
      mrun[r] = mn;
      acc[r] *= scr;
    }

#pragma unroll
    for (int kt = 0; kt < 4; ++kt)
#pragma unroll
      for (int r = 0; r < 4; ++r)
        Ps[w][g * 4 + r][kt * 16 + lr] = f2bf(sval[kt][r]);

    short8 pf0 = *(const short8*)&Ps[w][lr][g * 8];
    short8 pf1 = *(const short8*)&Ps[w][lr][32 + g * 8];
    short8 vf0 = *(const short8*)&Vt[lr][g * 8];
    short8 vf1 = *(const short8*)&Vt[lr][32 + g * 8];
    acc = __builtin_amdgcn_mfma_f32_16x16x32_bf16(pf0, vf0, acc, 0, 0, 0);
    acc = __builtin_amdgcn_mfma_f32_16x16x32_bf16(pf1, vf1, acc, 0, 0, 0);
    __syncthreads();
  }

#pragma unroll
  for (int r = 0; r < 4; ++r) {
    int q = qw + g * 4 + r;
    ctx[(size_t)q * D + h * DHD + lr] = f2bf(acc[r] / lrun[r]);
  }
}

// ---------------- launcher ----------------
extern "C" void kernel_launch(void* const* d_in, const int* in_sizes, int n_in,
                              void* d_out, int out_size, void* d_ws, size_t ws_size,
                              hipStream_t stream) {
  const float* x = (const float*)d_in[0];
  const float* ln0_g = (const float*)d_in[1];
  const float* ln0_b = (const float*)d_in[2];
  const float* lnq_g = (const float*)d_in[3];
  const float* lnq_b = (const float*)d_in[4];
  const float* lnk_g = (const float*)d_in[5];
  const float* lnk_b = (const float*)d_in[6];
  const float* lnv_g = (const float*)d_in[7];
  const float* lnv_b = (const float*)d_in[8];
  const float* Wq = (const float*)d_in[9];
  const float* bq = (const float*)d_in[10];
  const float* Wk = (const float*)d_in[11];
  const float* bk = (const float*)d_in[12];
  const float* Wv = (const float*)d_in[13];
  const float* bv = (const float*)d_in[14];
  const float* Wo = (const float*)d_in[15];
  const float* bo = (const float*)d_in[16];
  const float* lnf_g = (const float*)d_in[17];
  const float* lnf_b = (const float*)d_in[18];
  const float* W1 = (const float*)d_in[19];
  const float* b1 = (const float*)d_in[20];
  const float* W2 = (const float*)d_in[21];
  const float* b2 = (const float*)d_in[22];

  char* w = (char*)d_ws;
  size_t off = 0;
  auto alloc = [&](size_t bytes) -> void* {
    void* p = w + off;
    off += (bytes + 255) & ~(size_t)255;
    return p;
  };
  float* xn = (float*)alloc((size_t)S * D * 4);
  u16* qin = (u16*)alloc((size_t)S * D * 2);
  u16* kin = (u16*)alloc((size_t)S * D * 2);
  u16* vin = (u16*)alloc((size_t)S * D * 2);
  u16* Qb = (u16*)alloc((size_t)S * D * 2);
  u16* Kb = (u16*)alloc((size_t)S * D * 2);
  u16* Vb = (u16*)alloc((size_t)S * D * 2);
  u16* ctx = (u16*)alloc((size_t)S * D * 2);
  float* outb = (float*)alloc((size_t)S * D * 4);
  u16* lnf = (u16*)alloc((size_t)S * D * 2);
  u16* hbuf = (u16*)alloc((size_t)S * DFF * 2);
  u16* WqT = (u16*)alloc((size_t)D * D * 2);
  u16* WkT = (u16*)alloc((size_t)D * D * 2);
  u16* WvT = (u16*)alloc((size_t)D * D * 2);
  u16* WoT = (u16*)alloc((size_t)D * D * 2);
  u16* W1T = (u16*)alloc((size_t)DFF * D * 2);
  u16* W2T = (u16*)alloc((size_t)D * DFF * 2);

  dim3 tb(32, 8);
  transpose_bf16<<<dim3(D / 32, D / 32), tb, 0, stream>>>(Wq, WqT, D, D);
  transpose_bf16<<<dim3(D / 32, D / 32), tb, 0, stream>>>(Wk, WkT, D, D);
  transpose_bf16<<<dim3(D / 32, D / 32), tb, 0, stream>>>(Wv, WvT, D, D);
  transpose_bf16<<<dim3(D / 32, D / 32), tb, 0, stream>>>(Wo, WoT, D, D);
  transpose_bf16<<<dim3(DFF / 32, D / 32), tb, 0, stream>>>(W1, W1T, D, DFF);
  transpose_bf16<<<dim3(D / 32, DFF / 32), tb, 0, stream>>>(W2, W2T, DFF, D);

  ln0_kernel<<<S, 256, 0, stream>>>(x, ln0_g, ln0_b, lnq_g, lnq_b, lnk_g, lnk_b,
                                    lnv_g, lnv_b, xn, qin, kin, vin);

  gemm_kernel<false, false, true><<<dim3(S / 64, D / 64), 256, 0, stream>>>(
      qin, WqT, bq, nullptr, nullptr, Qb, S, D, D);
  gemm_kernel<false, false, true><<<dim3(S / 64, D / 64), 256, 0, stream>>>(
      kin, WkT, bk, nullptr, nullptr, Kb, S, D, D);
  gemm_kernel<false, false, true><<<dim3(S / 64, D / 64), 256, 0, stream>>>(
      vin, WvT, bv, nullptr, nullptr, Vb, S, D, D);

  attn_kernel<<<dim3(S / 64, NH), 256, 0, stream>>>(Qb, Kb, Vb, ctx);

  gemm_kernel<false, true, false><<<dim3(S / 64, D / 64), 256, 0, stream>>>(
      ctx, WoT, bo, xn, outb, nullptr, S, D, D);

  ln2_kernel<<<S, 256, 0, stream>>>(outb, lnf_g, lnf_b, lnf);

  gemm_kernel<true, false, true><<<dim3(S / 64, DFF / 64), 256, 0, stream>>>(
      lnf, W1T, b1, nullptr, nullptr, hbuf, S, DFF, D);

  gemm_kernel<true, true, false><<<dim3(S / 64, D / 64), 256, 0, stream>>>(
      hbuf, W2T, b2, outb, (float*)d_out, nullptr, S, D, DFF);

  (void)in_sizes; (void)n_in; (void)out_size; (void)ws_size;
}

// Round 2
// 149.545 us; speedup vs baseline: 1.2001x; 1.2001x over previous
//
#include <hip/hip_runtime.h>

#define S 2048
#define D 512
#define NH 32
#define DHD 16
#define DFF 1024
#define EPS 1e-5f
#define C1 0.36067376022224085f  // (1/sqrt(16)) * log2(e)

typedef unsigned short u16;
typedef __attribute__((ext_vector_type(8))) short short8;
typedef __attribute__((ext_vector_type(4))) float f32x4;
typedef __attribute__((ext_vector_type(16))) float f32x16;
typedef __attribute__((ext_vector_type(4))) unsigned short us4;

static __device__ __forceinline__ u16 f2bf(float f) {
  union { float f; unsigned int i; } c; c.f = f;
  unsigned int x = c.i;
  return (u16)((x + 0x7fffu + ((x >> 16) & 1u)) >> 16);
}

static __device__ __forceinline__ void block_reduce2(float& a, float& b, float* sm, int t) {
#pragma unroll
  for (int m = 1; m <= 32; m <<= 1) {
    a += __shfl_xor(a, m);
    b += __shfl_xor(b, m);
  }
  int w = t >> 6;
  if ((t & 63) == 0) { sm[w] = a; sm[4 + w] = b; }
  __syncthreads();
  a = sm[0] + sm[1] + sm[2] + sm[3];
  b = sm[4] + sm[5] + sm[6] + sm[7];
  __syncthreads();
}

// ---------------- LN kernels ----------------
__global__ __launch_bounds__(256) void ln0_kernel(
    const float* __restrict__ x,
    const float* __restrict__ g0, const float* __restrict__ b0,
    const float* __restrict__ gq, const float* __restrict__ bq,
    const float* __restrict__ gk, const float* __restrict__ bk,
    const float* __restrict__ gv, const float* __restrict__ bv,
    float* __restrict__ xn, u16* __restrict__ qin, u16* __restrict__ kin,
    u16* __restrict__ vin) {
  __shared__ float red[8];
  int row = blockIdx.x, t = threadIdx.x;
  const float* xr = x + (size_t)row * D;
  float a0 = xr[t], a1 = xr[t + 256];
  float s = a0 + a1, ss = a0 * a0 + a1 * a1;
  block_reduce2(s, ss, red, t);
  float mean = s * (1.0f / D);
  float var = ss * (1.0f / D) - mean * mean;
  float rs = rsqrtf(var + EPS);
  float y0 = (a0 - mean) * rs * g0[t] + b0[t];
  float y1 = (a1 - mean) * rs * g0[t + 256] + b0[t + 256];
  size_t o = (size_t)row * D + t;
  xn[o] = y0;
  xn[o + 256] = y1;
  float s2 = y0 + y1, ss2 = y0 * y0 + y1 * y1;
  block_reduce2(s2, ss2, red, t);
  float m2 = s2 * (1.0f / D);
  float v2 = ss2 * (1.0f / D) - m2 * m2;
  float rs2 = rsqrtf(v2 + EPS);
  float c0 = (y0 - m2) * rs2, c1 = (y1 - m2) * rs2;
  qin[o] = f2bf(c0 * gq[t] + bq[t]);
  qin[o + 256] = f2bf(c1 * gq[t + 256] + bq[t + 256]);
  kin[o] = f2bf(c0 * gk[t] + bk[t]);
  kin[o + 256] = f2bf(c1 * gk[t + 256] + bk[t + 256]);
  vin[o] = f2bf(c0 * gv[t] + bv[t]);
  vin[o + 256] = f2bf(c1 * gv[t + 256] + bv[t + 256]);
}

__global__ __launch_bounds__(256) void ln2_kernel(
    const float* __restrict__ in, const float* __restrict__ g,
    const float* __restrict__ b, u16* __restrict__ out) {
  __shared__ float red[8];
  int row = blockIdx.x, t = threadIdx.x;
  const float* xr = in + (size_t)row * D;
  float a0 = xr[t], a1 = xr[t + 256];
  float s = a0 + a1, ss = a0 * a0 + a1 * a1;
  block_reduce2(s, ss, red, t);
  float mean = s * (1.0f / D);
  float var = ss * (1.0f / D) - mean * mean;
  float rs = rsqrtf(var + EPS);
  size_t o = (size_t)row * D + t;
  out[o] = f2bf((a0 - mean) * rs * g[t] + b[t]);
  out[o + 256] = f2bf((a1 - mean) * rs * g[t + 256] + b[t + 256]);
}

// ---------------- weight transposes fp32 -> bf16 ----------------
static __device__ __forceinline__ void transpose_core(const float* __restrict__ W,
                                                      u16* __restrict__ Wt, int K, int N,
                                                      float (*tile)[33]) {
  int n0 = blockIdx.x * 32, k0 = blockIdx.y * 32;
  int tx = threadIdx.x, ty = threadIdx.y;  // (32,8)
#pragma unroll
  for (int i = 0; i < 4; ++i)
    tile[ty + 8 * i][tx] = W[(size_t)(k0 + ty + 8 * i) * N + n0 + tx];
  __syncthreads();
#pragma unroll
  for (int i = 0; i < 4; ++i)
    Wt[(size_t)(n0 + ty + 8 * i) * K + k0 + tx] = f2bf(tile[tx][ty + 8 * i]);
}

__global__ void transpose4(const float* __restrict__ W0, const float* __restrict__ W1,
                           const float* __restrict__ W2, const float* __restrict__ W3,
                           u16* __restrict__ T0, u16* __restrict__ T1,
                           u16* __restrict__ T2, u16* __restrict__ T3) {
  __shared__ float tile[32][33];
  int z = blockIdx.z;
  const float* W = z == 0 ? W0 : z == 1 ? W1 : z == 2 ? W2 : W3;
  u16* T = z == 0 ? T0 : z == 1 ? T1 : z == 2 ? T2 : T3;
  transpose_core(W, T, D, D, tile);
}

__global__ void transpose_bf16(const float* __restrict__ W, u16* __restrict__ Wt,
                               int K, int N) {
  __shared__ float tile[32][33];
  transpose_core(W, Wt, K, N, tile);
}

// ---------------- GEMM core: C[M,N] = A[M,K](bf16) @ Bt[N,K]^T + bias ----------------
template <bool RELU, bool RESID, bool OUTBF>
static __device__ __forceinline__ void gemm_core(
    const u16* __restrict__ A, const u16* __restrict__ Bt,
    const float* __restrict__ bias, const float* __restrict__ resid,
    float* __restrict__ outf, u16* __restrict__ outb, int N, int K, int m0, int n0,
    u16 (*As)[40], u16 (*Bs)[40]) {
  int t = threadIdx.x;
  int wid = t >> 6, lane = t & 63;
  int wm = wid >> 1, wn = wid & 1;
  int lrow = t >> 2, lcol = (t & 3) * 8;
  int g = lane >> 4, lr = lane & 15;
  f32x4 acc[2][2] = {};
  for (int kk = 0; kk < K; kk += 32) {
    uint4 av = *(const uint4*)(A + (size_t)(m0 + lrow) * K + kk + lcol);
    uint4 bv = *(const uint4*)(Bt + (size_t)(n0 + lrow) * K + kk + lcol);
    *(uint4*)&As[lrow][lcol] = av;
    *(uint4*)&Bs[lrow][lcol] = bv;
    __syncthreads();
    short8 af[2], bfm[2];
    af[0] = *(const short8*)&As[wm * 32 + lr][g * 8];
    af[1] = *(const short8*)&As[wm * 32 + 16 + lr][g * 8];
    bfm[0] = *(const short8*)&Bs[wn * 32 + lr][g * 8];
    bfm[1] = *(const short8*)&Bs[wn * 32 + 16 + lr][g * 8];
#pragma unroll
    for (int mi = 0; mi < 2; ++mi)
#pragma unroll
      for (int ni = 0; ni < 2; ++ni)
        acc[mi][ni] = __builtin_amdgcn_mfma_f32_16x16x32_bf16(
            af[mi], bfm[ni], acc[mi][ni], 0, 0, 0);
    __syncthreads();
  }
#pragma unroll
  for (int mi = 0; mi < 2; ++mi)
#pragma unroll
    for (int ni = 0; ni < 2; ++ni)
#pragma unroll
      for (int r = 0; r < 4; ++r) {
        int row = m0 + wm * 32 + mi * 16 + g * 4 + r;
        int col = n0 + wn * 32 + ni * 16 + lr;
        float v = acc[mi][ni][r] + bias[col];
        if (RELU) v = fmaxf(v, 0.0f);
        if (RESID) v += resid[(size_t)row * N + col];
        if (OUTBF)
          outb[(size_t)row * N + col] = f2bf(v);
        else
          outf[(size_t)row * N + col] = v;
      }
}

template <bool RELU, bool RESID, bool OUTBF>
__global__ __launch_bounds__(256) void gemm_kernel(
    const u16* __restrict__ A, const u16* __restrict__ Bt,
    const float* __restrict__ bias, const float* __restrict__ resid,
    float* __restrict__ outf, u16* __restrict__ outb, int N, int K) {
  __shared__ u16 As[64][40];
  __shared__ u16 Bs[64][40];
  gemm_core<RELU, RESID, OUTBF>(A, Bt, bias, resid, outf, outb, N, K,
                                blockIdx.x * 64, blockIdx.y * 64, As, Bs);
}

__global__ __launch_bounds__(256) void gemm_qkv(
    const u16* __restrict__ a0, const u16* __restrict__ a1, const u16* __restrict__ a2,
    const u16* __restrict__ w0, const u16* __restrict__ w1, const u16* __restrict__ w2,
    const float* __restrict__ c0, const float* __restrict__ c1, const float* __restrict__ c2,
    u16* __restrict__ o0, u16* __restrict__ o1, u16* __restrict__ o2) {
  __shared__ u16 As[64][40];
  __shared__ u16 Bs[64][40];
  int z = blockIdx.z;
  const u16* A = z == 0 ? a0 : z == 1 ? a1 : a2;
  const u16* Bt = z == 0 ? w0 : z == 1 ? w1 : w2;
  const float* bias = z == 0 ? c0 : z == 1 ? c1 : c2;
  u16* ob = z == 0 ? o0 : z == 1 ? o1 : o2;
  gemm_core<false, false, true>(A, Bt, bias, nullptr, nullptr, ob, D, D,
                                blockIdx.x * 64, blockIdx.y * 64, As, Bs);
}

// ---------------- causal flash attention (swapped 32x32 MFMA) ----------------
// 2 waves/block; wave w owns q rows [qt*64 + w*32, +32), head = blockIdx.y.
__global__ __launch_bounds__(128) void attn_kernel(const u16* __restrict__ Qb,
                                                   const u16* __restrict__ Kb,
                                                   const u16* __restrict__ Vb,
                                                   u16* __restrict__ ctx) {
  __shared__ u16 Klds[64][24];      // [kv][d], 16B-aligned rows
  __shared__ u16 Vt[16][72];        // [d][kv]
  __shared__ u16 Pst[2][32][72];    // per-wave [q][kv]

  const int t = threadIdx.x, w = t >> 6, lane = t & 63;
  const int h = blockIdx.y;
  const int qt = gridDim.x - 1 - blockIdx.x;  // longest-first
  const int q0w = qt * 64 + w * 32;
  const int lq = lane & 31, hi = lane >> 5;
  const int l16 = lane & 15, g4 = lane >> 4;
  const int qmaxw = q0w + 31;

  // Q fragment (B operand of swapped QK^T): lane -> q = q0w+lq, d = hi*8..+8
  short8 qf = *(const short8*)(Qb + (size_t)(q0w + lq) * D + h * DHD + hi * 8);

  f32x4 acc[2] = {};
  float Mrun = -1e30f, Lrun = 0.0f;

  const int srow = t >> 1, scol = (t & 1) * 8;
  const int ntiles = qt + 1;
  uint4 kreg = *(const uint4*)(Kb + (size_t)srow * D + h * DHD + scol);
  uint4 vreg = *(const uint4*)(Vb + (size_t)srow * D + h * DHD + scol);

  for (int tt = 0; tt < ntiles; ++tt) {
    const int kv0 = tt * 64;
    __syncthreads();
    *(uint4*)&Klds[srow][scol] = kreg;
    {
      unsigned int vv[4] = {vreg.x, vreg.y, vreg.z, vreg.w};
#pragma unroll
      for (int j = 0; j < 4; ++j) {
        Vt[scol + 2 * j][srow] = (u16)(vv[j] & 0xffffu);
        Vt[scol + 2 * j + 1][srow] = (u16)(vv[j] >> 16);
      }
    }
    __syncthreads();
    if (tt + 1 < ntiles) {
      kreg = *(const uint4*)(Kb + (size_t)(kv0 + 64 + srow) * D + h * DHD + scol);
      vreg = *(const uint4*)(Vb + (size_t)(kv0 + 64 + srow) * D + h * DHD + scol);
    }

    const bool v1 = (kv0 + 32) <= qmaxw;  // subtile 1 needed for this wave?
    float p[2][16];

    // ---- QK^T (swapped): S^T[kv][q] per 32-kv subtile ----
#pragma unroll
    for (int sx = 0; sx < 2; ++sx) {
      if (sx == 0 || v1) {
        short8 kf = *(const short8*)&Klds[sx * 32 + lq][hi * 8];
        f32x16 z = {};
        f32x16 st = __builtin_amdgcn_mfma_f32_32x32x16_bf16(kf, qf, z, 0, 0, 0);
        const bool needMask = (kv0 + sx * 32 + 31) > q0w;
#pragma unroll
        for (int r = 0; r < 16; ++r) {
          float tv = st[r] * C1;
          if (needMask) {
            int kv = kv0 + sx * 32 + (r & 3) + 8 * (r >> 2) + 4 * hi;
            if (kv > q0w + lq) tv = -1e30f;
          }
          p[sx][r] = tv;
        }
      }
    }

    // ---- online softmax (lane-local over kv, one cross-half exchange) ----
    float mx = p[0][0];
#pragma unroll
    for (int r = 1; r < 16; ++r) mx = fmaxf(mx, p[0][r]);
    if (v1) {
#pragma unroll
      for (int r = 0; r < 16; ++r) mx = fmaxf(mx, p[1][r]);
    }
    mx = fmaxf(mx, __shfl_xor(mx, 32));
    float Mnew = fmaxf(Mrun, mx);
    float corr = exp2f(Mrun - Mnew);
    float sum = 0.0f;
#pragma unroll
    for (int sx = 0; sx < 2; ++sx) {
      if (sx == 0 || v1) {
#pragma unroll
        for (int r = 0; r < 16; ++r) {
          float e = exp2f(p[sx][r] - Mnew);
          p[sx][r] = e;
          sum += e;
        }
      }
    }
    sum += __shfl_xor(sum, 32);
    Lrun = Lrun * corr + sum;
    Mrun = Mnew;

    // rescale accumulators (corr lives at lane = q_local; bpermute to acc layout)
#pragma unroll
    for (int sq = 0; sq < 2; ++sq)
#pragma unroll
      for (int r = 0; r < 4; ++r) {
        float c = __shfl(corr, sq * 16 + g4 * 4 + r);
        acc[sq][r] *= c;
      }

    // ---- pack P to bf16, store per-wave [q][kv] ----
#pragma unroll
    for (int sx = 0; sx < 2; ++sx) {
      if (sx == 0 || v1) {
#pragma unroll
        for (int k = 0; k < 4; ++k) {
          us4 pk;
#pragma unroll
          for (int j = 0; j < 4; ++j) pk[j] = f2bf(p[sx][4 * k + j]);
          *(us4*)&Pst[w][lq][sx * 32 + 8 * k + 4 * hi] = pk;
        }
      }
    }

    // ---- PV: acc[subQ] += P[q16][kv32] @ V[kv32][d16] ----
#pragma unroll
    for (int sx = 0; sx < 2; ++sx) {
      if (sx == 0 || v1) {
        short8 vf = *(const short8*)&Vt[l16][sx * 32 + g4 * 8];
#pragma unroll
        for (int sq = 0; sq < 2; ++sq) {
          short8 pf = *(const short8*)&Pst[w][sq * 16 + l16][sx * 32 + g4 * 8];
          acc[sq] = __builtin_amdgcn_mfma_f32_16x16x32_bf16(pf, vf, acc[sq], 0, 0, 0);
        }
      }
    }
  }

  // ---- epilogue: divide by L (bpermute from softmax layout), store ----
#pragma unroll
  for (int sq = 0; sq < 2; ++sq)
#pragma unroll
    for (int r = 0; r < 4; ++r) {
      int qlr = sq * 16 + g4 * 4 + r;
      float lv = __shfl(Lrun, qlr);
      ctx[(size_t)(q0w + qlr) * D + h * DHD + l16] = f2bf(acc[sq][r] / lv);
    }
}

// ---------------- launcher ----------------
extern "C" void kernel_launch(void* const* d_in, const int* in_sizes, int n_in,
                              void* d_out, int out_size, void* d_ws, size_t ws_size,
                              hipStream_t stream) {
  const float* x = (const float*)d_in[0];
  const float* ln0_g = (const float*)d_in[1];
  const float* ln0_b = (const float*)d_in[2];
  const float* lnq_g = (const float*)d_in[3];
  const float* lnq_b = (const float*)d_in[4];
  const float* lnk_g = (const float*)d_in[5];
  const float* lnk_b = (const float*)d_in[6];
  const float* lnv_g = (const float*)d_in[7];
  const float* lnv_b = (const float*)d_in[8];
  const float* Wq = (const float*)d_in[9];
  const float* bq = (const float*)d_in[10];
  const float* Wk = (const float*)d_in[11];
  const float* bk = (const float*)d_in[12];
  const float* Wv = (const float*)d_in[13];
  const float* bv = (const float*)d_in[14];
  const float* Wo = (const float*)d_in[15];
  const float* bo = (const float*)d_in[16];
  const float* lnf_g = (const float*)d_in[17];
  const float* lnf_b = (const float*)d_in[18];
  const float* W1 = (const float*)d_in[19];
  const float* b1 = (const float*)d_in[20];
  const float* W2 = (const float*)d_in[21];
  const float* b2 = (const float*)d_in[22];

  char* w = (char*)d_ws;
  size_t off = 0;
  auto alloc = [&](size_t bytes) -> void* {
    void* p = w + off;
    off += (bytes + 255) & ~(size_t)255;
    return p;
  };
  float* xn = (float*)alloc((size_t)S * D * 4);
  u16* qin = (u16*)alloc((size_t)S * D * 2);
  u16* kin = (u16*)alloc((size_t)S * D * 2);
  u16* vin = (u16*)alloc((size_t)S * D * 2);
  u16* Qb = (u16*)alloc((size_t)S * D * 2);
  u16* Kb = (u16*)alloc((size_t)S * D * 2);
  u16* Vb = (u16*)alloc((size_t)S * D * 2);
  u16* ctx = (u16*)alloc((size_t)S * D * 2);
  float* outb = (float*)alloc((size_t)S * D * 4);
  u16* lnf = (u16*)alloc((size_t)S * D * 2);
  u16* hbuf = (u16*)alloc((size_t)S * DFF * 2);
  u16* WqT = (u16*)alloc((size_t)D * D * 2);
  u16* WkT = (u16*)alloc((size_t)D * D * 2);
  u16* WvT = (u16*)alloc((size_t)D * D * 2);
  u16* WoT = (u16*)alloc((size_t)D * D * 2);
  u16* W1T = (u16*)alloc((size_t)DFF * D * 2);
  u16* W2T = (u16*)alloc((size_t)D * DFF * 2);

  dim3 tb(32, 8);
  transpose4<<<dim3(D / 32, D / 32, 4), tb, 0, stream>>>(Wq, Wk, Wv, Wo, WqT, WkT, WvT, WoT);
  transpose_bf16<<<dim3(DFF / 32, D / 32), tb, 0, stream>>>(W1, W1T, D, DFF);
  transpose_bf16<<<dim3(D / 32, DFF / 32), tb, 0, stream>>>(W2, W2T, DFF, D);

  ln0_kernel<<<S, 256, 0, stream>>>(x, ln0_g, ln0_b, lnq_g, lnq_b, lnk_g, lnk_b,
                                    lnv_g, lnv_b, xn, qin, kin, vin);

  gemm_qkv<<<dim3(S / 64, D / 64, 3), 256, 0, stream>>>(
      qin, kin, vin, WqT, WkT, WvT, bq, bk, bv, Qb, Kb, Vb);

  attn_kernel<<<dim3(S / 64, NH), 128, 0, stream>>>(Qb, Kb, Vb, ctx);

  gemm_kernel<false, true, false><<<dim3(S / 64, D / 64), 256, 0, stream>>>(
      ctx, WoT, bo, xn, outb, nullptr, D, D);

  ln2_kernel<<<S, 256, 0, stream>>>(outb, lnf_g, lnf_b, lnf);

  gemm_kernel<true, false, true><<<dim3(S / 64, DFF / 64), 256, 0, stream>>>(
      lnf, W1T, b1, nullptr, nullptr, hbuf, DFF, D);

  gemm_kernel<true, true, false><<<dim3(S / 64, D / 64), 256, 0, stream>>>(
      hbuf, W2T, b2, outb, (float*)d_out, nullptr, D, DFF);

  (void)in_sizes; (void)n_in; (void)out_size; (void)ws_size;
}

// Round 3
// 129.351 us; speedup vs baseline: 1.3875x; 1.1561x over previous
//
#include <hip/hip_runtime.h>

#define S 2048
#define D 512
#define NH 32
#define DHD 16
#define DFF 1024
#define EPS 1e-5f
#define C1 0.36067376022224085f  // (1/sqrt(16)) * log2(e)

typedef unsigned short u16;
typedef __attribute__((ext_vector_type(8))) short short8;
typedef __attribute__((ext_vector_type(4))) float f32x4;
typedef __attribute__((ext_vector_type(16))) float f32x16;
typedef __attribute__((ext_vector_type(4))) unsigned short us4;

static __device__ __forceinline__ u16 f2bf(float f) {
  union { float f; unsigned int i; } c; c.f = f;
  unsigned int x = c.i;
  return (u16)((x + 0x7fffu + ((x >> 16) & 1u)) >> 16);
}

static __device__ __forceinline__ void block_reduce2(float& a, float& b, float* sm, int t) {
#pragma unroll
  for (int m = 1; m <= 32; m <<= 1) {
    a += __shfl_xor(a, m);
    b += __shfl_xor(b, m);
  }
  int w = t >> 6;
  if ((t & 63) == 0) { sm[w] = a; sm[4 + w] = b; }
  __syncthreads();
  a = sm[0] + sm[1] + sm[2] + sm[3];
  b = sm[4] + sm[5] + sm[6] + sm[7];
  __syncthreads();
}

// ---------------- LN kernels ----------------
__global__ __launch_bounds__(256) void ln0_kernel(
    const float* __restrict__ x,
    const float* __restrict__ g0, const float* __restrict__ b0,
    const float* __restrict__ gq, const float* __restrict__ bq,
    const float* __restrict__ gk, const float* __restrict__ bk,
    const float* __restrict__ gv, const float* __restrict__ bv,
    float* __restrict__ xn, u16* __restrict__ qin, u16* __restrict__ kin,
    u16* __restrict__ vin) {
  __shared__ float red[8];
  int row = blockIdx.x, t = threadIdx.x;
  const float* xr = x + (size_t)row * D;
  float a0 = xr[t], a1 = xr[t + 256];
  float s = a0 + a1, ss = a0 * a0 + a1 * a1;
  block_reduce2(s, ss, red, t);
  float mean = s * (1.0f / D);
  float var = ss * (1.0f / D) - mean * mean;
  float rs = rsqrtf(var + EPS);
  float y0 = (a0 - mean) * rs * g0[t] + b0[t];
  float y1 = (a1 - mean) * rs * g0[t + 256] + b0[t + 256];
  size_t o = (size_t)row * D + t;
  xn[o] = y0;
  xn[o + 256] = y1;
  float s2 = y0 + y1, ss2 = y0 * y0 + y1 * y1;
  block_reduce2(s2, ss2, red, t);
  float m2 = s2 * (1.0f / D);
  float v2 = ss2 * (1.0f / D) - m2 * m2;
  float rs2 = rsqrtf(v2 + EPS);
  float c0 = (y0 - m2) * rs2, c1 = (y1 - m2) * rs2;
  qin[o] = f2bf(c0 * gq[t] + bq[t]);
  qin[o + 256] = f2bf(c1 * gq[t + 256] + bq[t + 256]);
  kin[o] = f2bf(c0 * gk[t] + bk[t]);
  kin[o + 256] = f2bf(c1 * gk[t + 256] + bk[t + 256]);
  vin[o] = f2bf(c0 * gv[t] + bv[t]);
  vin[o + 256] = f2bf(c1 * gv[t + 256] + bv[t + 256]);
}

__global__ __launch_bounds__(256) void ln2_kernel(
    const float* __restrict__ in, const float* __restrict__ g,
    const float* __restrict__ b, u16* __restrict__ out) {
  __shared__ float red[8];
  int row = blockIdx.x, t = threadIdx.x;
  const float* xr = in + (size_t)row * D;
  float a0 = xr[t], a1 = xr[t + 256];
  float s = a0 + a1, ss = a0 * a0 + a1 * a1;
  block_reduce2(s, ss, red, t);
  float mean = s * (1.0f / D);
  float var = ss * (1.0f / D) - mean * mean;
  float rs = rsqrtf(var + EPS);
  size_t o = (size_t)row * D + t;
  out[o] = f2bf((a0 - mean) * rs * g[t] + b[t]);
  out[o + 256] = f2bf((a1 - mean) * rs * g[t + 256] + b[t + 256]);
}

// ---------------- weight transposes fp32 -> bf16 ----------------
static __device__ __forceinline__ void transpose_core(const float* __restrict__ W,
                                                      u16* __restrict__ Wt, int K, int N,
                                                      float (*tile)[33]) {
  int n0 = blockIdx.x * 32, k0 = blockIdx.y * 32;
  int tx = threadIdx.x, ty = threadIdx.y;  // (32,8)
#pragma unroll
  for (int i = 0; i < 4; ++i)
    tile[ty + 8 * i][tx] = W[(size_t)(k0 + ty + 8 * i) * N + n0 + tx];
  __syncthreads();
#pragma unroll
  for (int i = 0; i < 4; ++i)
    Wt[(size_t)(n0 + ty + 8 * i) * K + k0 + tx] = f2bf(tile[tx][ty + 8 * i]);
}

__global__ void transpose4(const float* __restrict__ W0, const float* __restrict__ W1,
                           const float* __restrict__ W2, const float* __restrict__ W3,
                           u16* __restrict__ T0, u16* __restrict__ T1,
                           u16* __restrict__ T2, u16* __restrict__ T3) {
  __shared__ float tile[32][33];
  int z = blockIdx.z;
  const float* W = z == 0 ? W0 : z == 1 ? W1 : z == 2 ? W2 : W3;
  u16* T = z == 0 ? T0 : z == 1 ? T1 : z == 2 ? T2 : T3;
  transpose_core(W, T, D, D, tile);
}

__global__ void transpose_bf16(const float* __restrict__ W, u16* __restrict__ Wt,
                               int K, int N) {
  __shared__ float tile[32][33];
  transpose_core(W, Wt, K, N, tile);
}

// ---------------- GEMM core ----------------
template <bool RELU, bool RESID, bool OUTBF>
static __device__ __forceinline__ void gemm_core(
    const u16* __restrict__ A, const u16* __restrict__ Bt,
    const float* __restrict__ bias, const float* __restrict__ resid,
    float* __restrict__ outf, u16* __restrict__ outb, int N, int K, int m0, int n0,
    u16 (*As)[40], u16 (*Bs)[40]) {
  int t = threadIdx.x;
  int wid = t >> 6, lane = t & 63;
  int wm = wid >> 1, wn = wid & 1;
  int lrow = t >> 2, lcol = (t & 3) * 8;
  int g = lane >> 4, lr = lane & 15;
  f32x4 acc[2][2] = {};
  for (int kk = 0; kk < K; kk += 32) {
    uint4 av = *(const uint4*)(A + (size_t)(m0 + lrow) * K + kk + lcol);
    uint4 bv = *(const uint4*)(Bt + (size_t)(n0 + lrow) * K + kk + lcol);
    *(uint4*)&As[lrow][lcol] = av;
    *(uint4*)&Bs[lrow][lcol] = bv;
    __syncthreads();
    short8 af[2], bfm[2];
    af[0] = *(const short8*)&As[wm * 32 + lr][g * 8];
    af[1] = *(const short8*)&As[wm * 32 + 16 + lr][g * 8];
    bfm[0] = *(const short8*)&Bs[wn * 32 + lr][g * 8];
    bfm[1] = *(const short8*)&Bs[wn * 32 + 16 + lr][g * 8];
#pragma unroll
    for (int mi = 0; mi < 2; ++mi)
#pragma unroll
      for (int ni = 0; ni < 2; ++ni)
        acc[mi][ni] = __builtin_amdgcn_mfma_f32_16x16x32_bf16(
            af[mi], bfm[ni], acc[mi][ni], 0, 0, 0);
    __syncthreads();
  }
#pragma unroll
  for (int mi = 0; mi < 2; ++mi)
#pragma unroll
    for (int ni = 0; ni < 2; ++ni)
#pragma unroll
      for (int r = 0; r < 4; ++r) {
        int row = m0 + wm * 32 + mi * 16 + g * 4 + r;
        int col = n0 + wn * 32 + ni * 16 + lr;
        float v = acc[mi][ni][r] + bias[col];
        if (RELU) v = fmaxf(v, 0.0f);
        if (RESID) v += resid[(size_t)row * N + col];
        if (OUTBF)
          outb[(size_t)row * N + col] = f2bf(v);
        else
          outf[(size_t)row * N + col] = v;
      }
}

template <bool RELU, bool RESID, bool OUTBF>
__global__ __launch_bounds__(256) void gemm_kernel(
    const u16* __restrict__ A, const u16* __restrict__ Bt,
    const float* __restrict__ bias, const float* __restrict__ resid,
    float* __restrict__ outf, u16* __restrict__ outb, int N, int K) {
  __shared__ u16 As[64][40];
  __shared__ u16 Bs[64][40];
  gemm_core<RELU, RESID, OUTBF>(A, Bt, bias, resid, outf, outb, N, K,
                                blockIdx.x * 64, blockIdx.y * 64, As, Bs);
}

__global__ __launch_bounds__(256) void gemm_qkv(
    const u16* __restrict__ a0, const u16* __restrict__ a1, const u16* __restrict__ a2,
    const u16* __restrict__ w0, const u16* __restrict__ w1, const u16* __restrict__ w2,
    const float* __restrict__ c0, const float* __restrict__ c1, const float* __restrict__ c2,
    u16* __restrict__ o0, u16* __restrict__ o1, u16* __restrict__ o2) {
  __shared__ u16 As[64][40];
  __shared__ u16 Bs[64][40];
  int z = blockIdx.z;
  const u16* A = z == 0 ? a0 : z == 1 ? a1 : a2;
  const u16* Bt = z == 0 ? w0 : z == 1 ? w1 : w2;
  const float* bias = z == 0 ? c0 : z == 1 ? c1 : c2;
  u16* ob = z == 0 ? o0 : z == 1 ? o1 : o2;
  gemm_core<false, false, true>(A, Bt, bias, nullptr, nullptr, ob, D, D,
                                blockIdx.x * 64, blockIdx.y * 64, As, Bs);
}

// ---------------- K/V fragment-layout prep ----------------
// KtG: [h][kv32][hi][lq(32)][8]  (K fragment rows, d = hi*8+j)
// VtG: [h][kv32][g4][d(16)][8]   (V^T fragment, kv = kv32*32+g4*8+j)
__global__ __launch_bounds__(128) void qkv_prep(const u16* __restrict__ Kb,
                                                const u16* __restrict__ Vb,
                                                u16* __restrict__ KtG,
                                                u16* __restrict__ VtG) {
  int t = threadIdx.x;
  int kv0 = blockIdx.x * 64;
  int h = blockIdx.y;
  {
    int kv = kv0 + (t >> 1), hi = t & 1;
    uint4 kval = *(const uint4*)(Kb + (size_t)kv * D + h * DHD + hi * 8);
    int kv32 = kv >> 5, lq = kv & 31;
    *(uint4*)(KtG + ((((size_t)h * 64 + kv32) * 2 + hi) * 32 + lq) * 8) = kval;
  }
  {
    int kv32l = t >> 6, g4 = (t >> 4) & 3, d = t & 15;
    int kvb = kv0 + kv32l * 32 + g4 * 8;
    us4 a, b;
#pragma unroll
    for (int j = 0; j < 4; ++j) a[j] = Vb[(size_t)(kvb + j) * D + h * DHD + d];
#pragma unroll
    for (int j = 0; j < 4; ++j) b[j] = Vb[(size_t)(kvb + 4 + j) * D + h * DHD + d];
    int kv32 = (kv0 >> 5) + kv32l;
    u16* dst = VtG + ((((size_t)h * 64 + kv32) * 4 + g4) * 16 + d) * 8;
    *(us4*)dst = a;
    *(us4*)(dst + 4) = b;
  }
}

// ---------------- causal flash attention, split-KV ----------------
// Block = (chunk-slot f, head). Chunk = up to 8 tiles of 64 kv.
// 2 waves; wave w owns q rows [qt*64 + w*32, +32).
__global__ __launch_bounds__(128) void attn_kernel(const u16* __restrict__ Qb,
                                                   const u16* __restrict__ KtG,
                                                   const u16* __restrict__ VtG,
                                                   u16* __restrict__ ctx,
                                                   float* __restrict__ part) {
  __shared__ u16 Kl[2][2][32][8];        // 2KB  [kv32][hi][lq][j]
  __shared__ u16 Vl[2][4][16][8];        // 2KB  [kv32][g4][d][j]
  __shared__ u16 Pl[2][2][2][4][16][8];  // 16KB [w][sq][sx][g4][l16][j]

  const int t = threadIdx.x, w = t >> 6, lane = t & 63;
  const int h = blockIdx.y;
  const int f = 79 - blockIdx.x;  // longest-first
  int qt, c;
  if (f < 8) { qt = f; c = 0; }
  else if (f < 24) { int g = f - 8; qt = 8 + (g >> 1); c = g & 1; }
  else if (f < 48) { int g = f - 24; qt = 16 + g / 3; c = g % 3; }
  else { int g = f - 48; qt = 24 + (g >> 2); c = g & 3; }
  const int tile0 = c * 8;
  const int tile1 = (tile0 + 7 < qt) ? tile0 + 7 : qt;
  const bool multi = (qt >= 8);

  const int q0w = qt * 64 + w * 32;
  const int lq = lane & 31, hi = lane >> 5;
  const int l16 = lane & 15, g4 = lane >> 4;

  short8 qf = *(const short8*)(Qb + (size_t)(q0w + lq) * D + h * DHD + hi * 8);

  const u16* Kt_h = KtG + (size_t)h * 32768;
  const u16* Vt_h = VtG + (size_t)h * 32768;

  f32x4 acc[2] = {};
  float Mrun = -1e30f, Lrun = 0.0f;

  uint4 kreg = *(const uint4*)(Kt_h + (size_t)tile0 * 1024 + t * 8);
  uint4 vreg = *(const uint4*)(Vt_h + (size_t)tile0 * 1024 + t * 8);

  for (int tt = tile0; tt <= tile1; ++tt) {
    __syncthreads();
    *(uint4*)((u16*)Kl + t * 8) = kreg;
    *(uint4*)((u16*)Vl + t * 8) = vreg;
    __syncthreads();
    if (tt < tile1) {
      kreg = *(const uint4*)(Kt_h + (size_t)(tt + 1) * 1024 + t * 8);
      vreg = *(const uint4*)(Vt_h + (size_t)(tt + 1) * 1024 + t * 8);
    }
    const int kv0 = tt * 64;
    const bool v1 = (kv0 + 32) <= (q0w + 31);
    float p[2][16];

    // ---- QK^T (swapped): S^T[kv][q] ----
#pragma unroll
    for (int sx = 0; sx < 2; ++sx) {
      if (sx == 0 || v1) {
        short8 kf = *(const short8*)&Kl[sx][hi][lq][0];
        f32x16 z = {};
        f32x16 st = __builtin_amdgcn_mfma_f32_32x32x16_bf16(kf, qf, z, 0, 0, 0);
        const bool needMask = (kv0 + sx * 32 + 31) > q0w;
#pragma unroll
        for (int r = 0; r < 16; ++r) {
          float tv = st[r] * C1;
          if (needMask) {
            int kv = kv0 + sx * 32 + (r & 3) + 8 * (r >> 2) + 4 * hi;
            if (kv > q0w + lq) tv = -1e30f;
          }
          p[sx][r] = tv;
        }
      }
    }

    // ---- online softmax (lane-local over kv, one cross-half exchange) ----
    float mx = p[0][0];
#pragma unroll
    for (int r = 1; r < 16; ++r) mx = fmaxf(mx, p[0][r]);
    if (v1) {
#pragma unroll
      for (int r = 0; r < 16; ++r) mx = fmaxf(mx, p[1][r]);
    }
    mx = fmaxf(mx, __shfl_xor(mx, 32));
    float Mnew = fmaxf(Mrun, mx);
    float corr = exp2f(Mrun - Mnew);
    float sum = 0.0f;
#pragma unroll
    for (int sx = 0; sx < 2; ++sx) {
      if (sx == 0 || v1) {
#pragma unroll
        for (int r = 0; r < 16; ++r) {
          float e = exp2f(p[sx][r] - Mnew);
          p[sx][r] = e;
          sum += e;
        }
      }
    }
    sum += __shfl_xor(sum, 32);
    Lrun = Lrun * corr + sum;
    Mrun = Mnew;

#pragma unroll
    for (int sq = 0; sq < 2; ++sq)
#pragma unroll
      for (int r = 0; r < 4; ++r) {
        float cc = __shfl(corr, sq * 16 + g4 * 4 + r);
        acc[sq][r] *= cc;
      }

    // ---- pack P to bf16 into fragment-tiled LDS ----
#pragma unroll
    for (int sx = 0; sx < 2; ++sx) {
      if (sx == 0 || v1) {
#pragma unroll
        for (int k = 0; k < 4; ++k) {
          us4 pk;
#pragma unroll
          for (int j = 0; j < 4; ++j) pk[j] = f2bf(p[sx][4 * k + j]);
          *(us4*)&Pl[w][lq >> 4][sx][k][lq & 15][4 * hi] = pk;
        }
      }
    }

    // ---- PV ----
#pragma unroll
    for (int sx = 0; sx < 2; ++sx) {
      if (sx == 0 || v1) {
        short8 vf = *(const short8*)&Vl[sx][g4][l16][0];
#pragma unroll
        for (int sq = 0; sq < 2; ++sq) {
          short8 pf = *(const short8*)&Pl[w][sq][sx][g4][l16][0];
          acc[sq] = __builtin_amdgcn_mfma_f32_16x16x32_bf16(pf, vf, acc[sq], 0, 0, 0);
        }
      }
    }
  }

  if (!multi) {
#pragma unroll
    for (int sq = 0; sq < 2; ++sq)
#pragma unroll
      for (int r = 0; r < 4; ++r) {
        int qlr = sq * 16 + g4 * 4 + r;
        float lv = __shfl(Lrun, qlr);
        ctx[(size_t)(q0w + qlr) * D + h * DHD + l16] = f2bf(acc[sq][r] / lv);
      }
  } else {
    float* ps = part + (((size_t)h * 24 + (qt - 8)) * 4 + c) * (64 * 18);
#pragma unroll
    for (int sq = 0; sq < 2; ++sq)
#pragma unroll
      for (int r = 0; r < 4; ++r) {
        int qlocal = w * 32 + sq * 16 + g4 * 4 + r;
        ps[qlocal * 18 + 2 + l16] = acc[sq][r];
      }
    if (hi == 0) {
      ps[(w * 32 + lq) * 18 + 0] = Mrun;
      ps[(w * 32 + lq) * 18 + 1] = Lrun;
    }
  }
}

// ---------------- merge split-KV partials ----------------
__global__ __launch_bounds__(64) void attn_merge(const float* __restrict__ part,
                                                 u16* __restrict__ ctx) {
  int qt8 = blockIdx.x, h = blockIdx.y, tq = threadIdx.x;
  int qt = 8 + qt8;
  int nc = qt / 8 + 1;
  const float* base = part + ((size_t)h * 24 + qt8) * 4 * (64 * 18);
  float M = -1e30f;
  for (int c = 0; c < nc; ++c) M = fmaxf(M, base[c * 1152 + tq * 18]);
  float L = 0.0f;
  float o[16];
#pragma unroll
  for (int d = 0; d < 16; ++d) o[d] = 0.0f;
  for (int c = 0; c < nc; ++c) {
    const float* pr = base + c * 1152 + tq * 18;
    float sc = exp2f(pr[0] - M);
    L += pr[1] * sc;
#pragma unroll
    for (int d = 0; d < 16; ++d) o[d] += pr[2 + d] * sc;
  }
  float inv = 1.0f / L;
  int q = qt * 64 + tq;
  u16* op = ctx + (size_t)q * D + h * DHD;
#pragma unroll
  for (int k = 0; k < 4; ++k) {
    us4 pk;
#pragma unroll
    for (int j = 0; j < 4; ++j) pk[j] = f2bf(o[4 * k + j] * inv);
    *(us4*)(op + 4 * k) = pk;
  }
}

// ---------------- launcher ----------------
extern "C" void kernel_launch(void* const* d_in, const int* in_sizes, int n_in,
                              void* d_out, int out_size, void* d_ws, size_t ws_size,
                              hipStream_t stream) {
  const float* x = (const float*)d_in[0];
  const float* ln0_g = (const float*)d_in[1];
  const float* ln0_b = (const float*)d_in[2];
  const float* lnq_g = (const float*)d_in[3];
  const float* lnq_b = (const float*)d_in[4];
  const float* lnk_g = (const float*)d_in[5];
  const float* lnk_b = (const float*)d_in[6];
  const float* lnv_g = (const float*)d_in[7];
  const float* lnv_b = (const float*)d_in[8];
  const float* Wq = (const float*)d_in[9];
  const float* bq = (const float*)d_in[10];
  const float* Wk = (const float*)d_in[11];
  const float* bk = (const float*)d_in[12];
  const float* Wv = (const float*)d_in[13];
  const float* bv = (const float*)d_in[14];
  const float* Wo = (const float*)d_in[15];
  const float* bo = (const float*)d_in[16];
  const float* lnf_g = (const float*)d_in[17];
  const float* lnf_b = (const float*)d_in[18];
  const float* W1 = (const float*)d_in[19];
  const float* b1 = (const float*)d_in[20];
  const float* W2 = (const float*)d_in[21];
  const float* b2 = (const float*)d_in[22];

  char* wsp = (char*)d_ws;
  size_t off = 0;
  auto alloc = [&](size_t bytes) -> void* {
    void* p = wsp + off;
    off += (bytes + 255) & ~(size_t)255;
    return p;
  };
  // ---- fixed region (live across attention) ----
  float* xn = (float*)alloc((size_t)S * D * 4);
  u16* Qb = (u16*)alloc((size_t)S * D * 2);
  u16* Kb = (u16*)alloc((size_t)S * D * 2);
  u16* Vb = (u16*)alloc((size_t)S * D * 2);
  u16* ctx = (u16*)alloc((size_t)S * D * 2);
  u16* KtG = (u16*)alloc((size_t)S * D * 2);
  u16* VtG = (u16*)alloc((size_t)S * D * 2);
  u16* WqT = (u16*)alloc((size_t)D * D * 2);
  u16* WkT = (u16*)alloc((size_t)D * D * 2);
  u16* WvT = (u16*)alloc((size_t)D * D * 2);
  u16* WoT = (u16*)alloc((size_t)D * D * 2);
  u16* W1T = (u16*)alloc((size_t)D * DFF * 2);
  u16* W2T = (u16*)alloc((size_t)DFF * D * 2);
  // ---- multiplexed region B (phases don't overlap in stream order) ----
  char* regB = (char*)alloc((size_t)32 * 24 * 4 * 64 * 18 * 4);  // 14.16MB
  u16* qin = (u16*)regB;                                 // phase 1
  u16* kin = (u16*)(regB + (size_t)S * D * 2);
  u16* vin = (u16*)(regB + (size_t)S * D * 4);
  float* part = (float*)regB;                            // phase 2
  float* outb = (float*)regB;                            // phase 3
  u16* lnf = (u16*)(regB + (size_t)S * D * 4);
  u16* hbuf = (u16*)(regB + (size_t)S * D * 6);

  dim3 tb(32, 8);
  transpose4<<<dim3(D / 32, D / 32, 4), tb, 0, stream>>>(Wq, Wk, Wv, Wo, WqT, WkT, WvT, WoT);
  transpose_bf16<<<dim3(DFF / 32, D / 32), tb, 0, stream>>>(W1, W1T, D, DFF);
  transpose_bf16<<<dim3(D / 32, DFF / 32), tb, 0, stream>>>(W2, W2T, DFF, D);

  ln0_kernel<<<S, 256, 0, stream>>>(x, ln0_g, ln0_b, lnq_g, lnq_b, lnk_g, lnk_b,
                                    lnv_g, lnv_b, xn, qin, kin, vin);

  gemm_qkv<<<dim3(S / 64, D / 64, 3), 256, 0, stream>>>(
      qin, kin, vin, WqT, WkT, WvT, bq, bk, bv, Qb, Kb, Vb);

  qkv_prep<<<dim3(S / 64, NH), 128, 0, stream>>>(Kb, Vb, KtG, VtG);

  attn_kernel<<<dim3(80, NH), 128, 0, stream>>>(Qb, KtG, VtG, ctx, part);

  attn_merge<<<dim3(24, NH), 64, 0, stream>>>(part, ctx);

  gemm_kernel<false, true, false><<<dim3(S / 64, D / 64), 256, 0, stream>>>(
      ctx, WoT, bo, xn, outb, nullptr, D, D);

  ln2_kernel<<<S, 256, 0, stream>>>(outb, lnf_g, lnf_b, lnf);

  gemm_kernel<true, false, true><<<dim3(S / 64, DFF / 64), 256, 0, stream>>>(
      lnf, W1T, b1, nullptr, nullptr, hbuf, DFF, D);

  gemm_kernel<true, true, false><<<dim3(S / 64, D / 64), 256, 0, stream>>>(
      hbuf, W2T, b2, outb, (float*)d_out, nullptr, D, DFF);

  (void)in_sizes; (void)n_in; (void)out_size; (void)ws_size;
}

// Round 4
// 114.234 us; speedup vs baseline: 1.5711x; 1.1323x over previous
//
#include <hip/hip_runtime.h>

#define S 2048
#define D 512
#define NH 32
#define DHD 16
#define DFF 1024
#define EPS 1e-5f
#define C1 0.36067376022224085f  // (1/sqrt(16)) * log2(e)

typedef unsigned short u16;
typedef __attribute__((ext_vector_type(8))) short short8;
typedef __attribute__((ext_vector_type(4))) float f32x4;
typedef __attribute__((ext_vector_type(16))) float f32x16;
typedef __attribute__((ext_vector_type(4))) unsigned short us4;

static __device__ __forceinline__ u16 f2bf(float f) {
  union { float f; unsigned int i; } c; c.f = f;
  unsigned int x = c.i;
  return (u16)((x + 0x7fffu + ((x >> 16) & 1u)) >> 16);
}
static __device__ __forceinline__ float bf2f(u16 v) {
  union { unsigned int i; float f; } c; c.i = ((unsigned int)v) << 16;
  return c.f;
}

static __device__ __forceinline__ void block_reduce2(float& a, float& b, float* sm, int t) {
#pragma unroll
  for (int m = 1; m <= 32; m <<= 1) {
    a += __shfl_xor(a, m);
    b += __shfl_xor(b, m);
  }
  int w = t >> 6;
  if ((t & 63) == 0) { sm[w] = a; sm[4 + w] = b; }
  __syncthreads();
  a = sm[0] + sm[1] + sm[2] + sm[3];
  b = sm[4] + sm[5] + sm[6] + sm[7];
  __syncthreads();
}

// ---------------- LN kernels ----------------
__global__ __launch_bounds__(256) void ln0_kernel(
    const float* __restrict__ x,
    const float* __restrict__ g0, const float* __restrict__ b0,
    const float* __restrict__ gq, const float* __restrict__ bq,
    const float* __restrict__ gk, const float* __restrict__ bk,
    const float* __restrict__ gv, const float* __restrict__ bv,
    float* __restrict__ xn, u16* __restrict__ qin, u16* __restrict__ kin,
    u16* __restrict__ vin) {
  __shared__ float red[8];
  int row = blockIdx.x, t = threadIdx.x;
  const float* xr = x + (size_t)row * D;
  float a0 = xr[t], a1 = xr[t + 256];
  float s = a0 + a1, ss = a0 * a0 + a1 * a1;
  block_reduce2(s, ss, red, t);
  float mean = s * (1.0f / D);
  float var = ss * (1.0f / D) - mean * mean;
  float rs = rsqrtf(var + EPS);
  float y0 = (a0 - mean) * rs * g0[t] + b0[t];
  float y1 = (a1 - mean) * rs * g0[t + 256] + b0[t + 256];
  size_t o = (size_t)row * D + t;
  xn[o] = y0;
  xn[o + 256] = y1;
  float s2 = y0 + y1, ss2 = y0 * y0 + y1 * y1;
  block_reduce2(s2, ss2, red, t);
  float m2 = s2 * (1.0f / D);
  float v2 = ss2 * (1.0f / D) - m2 * m2;
  float rs2 = rsqrtf(v2 + EPS);
  float c0 = (y0 - m2) * rs2, c1 = (y1 - m2) * rs2;
  qin[o] = f2bf(c0 * gq[t] + bq[t]);
  qin[o + 256] = f2bf(c1 * gq[t + 256] + bq[t + 256]);
  kin[o] = f2bf(c0 * gk[t] + bk[t]);
  kin[o + 256] = f2bf(c1 * gk[t + 256] + bk[t + 256]);
  vin[o] = f2bf(c0 * gv[t] + bv[t]);
  vin[o + 256] = f2bf(c1 * gv[t + 256] + bv[t + 256]);
}

__global__ __launch_bounds__(256) void ln2_kernel(
    const float* __restrict__ in, const float* __restrict__ g,
    const float* __restrict__ b, u16* __restrict__ out) {
  __shared__ float red[8];
  int row = blockIdx.x, t = threadIdx.x;
  const float* xr = in + (size_t)row * D;
  float a0 = xr[t], a1 = xr[t + 256];
  float s = a0 + a1, ss = a0 * a0 + a1 * a1;
  block_reduce2(s, ss, red, t);
  float mean = s * (1.0f / D);
  float var = ss * (1.0f / D) - mean * mean;
  float rs = rsqrtf(var + EPS);
  size_t o = (size_t)row * D + t;
  out[o] = f2bf((a0 - mean) * rs * g[t] + b[t]);
  out[o + 256] = f2bf((a1 - mean) * rs * g[t + 256] + b[t + 256]);
}

// ---------------- weight transposes fp32 -> bf16 ----------------
static __device__ __forceinline__ void transpose_core(const float* __restrict__ W,
                                                      u16* __restrict__ Wt, int K, int N,
                                                      float (*tile)[33]) {
  int n0 = blockIdx.x * 32, k0 = blockIdx.y * 32;
  int tx = threadIdx.x, ty = threadIdx.y;  // (32,8)
#pragma unroll
  for (int i = 0; i < 4; ++i)
    tile[ty + 8 * i][tx] = W[(size_t)(k0 + ty + 8 * i) * N + n0 + tx];
  __syncthreads();
#pragma unroll
  for (int i = 0; i < 4; ++i)
    Wt[(size_t)(n0 + ty + 8 * i) * K + k0 + tx] = f2bf(tile[tx][ty + 8 * i]);
}

__global__ void transpose4(const float* __restrict__ W0, const float* __restrict__ W1,
                           const float* __restrict__ W2, const float* __restrict__ W3,
                           u16* __restrict__ T0, u16* __restrict__ T1,
                           u16* __restrict__ T2, u16* __restrict__ T3) {
  __shared__ float tile[32][33];
  int z = blockIdx.z;
  const float* W = z == 0 ? W0 : z == 1 ? W1 : z == 2 ? W2 : W3;
  u16* T = z == 0 ? T0 : z == 1 ? T1 : z == 2 ? T2 : T3;
  transpose_core(W, T, D, D, tile);
}

__global__ void transpose_bf16(const float* __restrict__ W, u16* __restrict__ Wt,
                               int K, int N) {
  __shared__ float tile[32][33];
  transpose_core(W, Wt, K, N, tile);
}

// ---------------- GEMM accumulate core (double-buffered, 1 barrier/step) ----------------
static __device__ __forceinline__ void gemm_acc(
    const u16* __restrict__ A, const u16* __restrict__ Bt, int K, int m0, int n0,
    u16 (*As)[64][40], u16 (*Bs)[64][40], f32x4 acc[2][2]) {
  int t = threadIdx.x;
  int wid = t >> 6, lane = t & 63;
  int wm = wid >> 1, wn = wid & 1;
  int lrow = t >> 2, lcol = (t & 3) * 8;
  int g = lane >> 4, lr = lane & 15;
  uint4 av = *(const uint4*)(A + (size_t)(m0 + lrow) * K + lcol);
  uint4 bv = *(const uint4*)(Bt + (size_t)(n0 + lrow) * K + lcol);
  *(uint4*)&As[0][lrow][lcol] = av;
  *(uint4*)&Bs[0][lrow][lcol] = bv;
  __syncthreads();
  int p = 0;
  for (int kk = 0; kk < K; kk += 32) {
    if (kk + 32 < K) {
      av = *(const uint4*)(A + (size_t)(m0 + lrow) * K + kk + 32 + lcol);
      bv = *(const uint4*)(Bt + (size_t)(n0 + lrow) * K + kk + 32 + lcol);
    }
    short8 af[2], bfm[2];
    af[0] = *(const short8*)&As[p][wm * 32 + lr][g * 8];
    af[1] = *(const short8*)&As[p][wm * 32 + 16 + lr][g * 8];
    bfm[0] = *(const short8*)&Bs[p][wn * 32 + lr][g * 8];
    bfm[1] = *(const short8*)&Bs[p][wn * 32 + 16 + lr][g * 8];
#pragma unroll
    for (int mi = 0; mi < 2; ++mi)
#pragma unroll
      for (int ni = 0; ni < 2; ++ni)
        acc[mi][ni] = __builtin_amdgcn_mfma_f32_16x16x32_bf16(
            af[mi], bfm[ni], acc[mi][ni], 0, 0, 0);
    if (kk + 32 < K) {
      *(uint4*)&As[p ^ 1][lrow][lcol] = av;
      *(uint4*)&Bs[p ^ 1][lrow][lcol] = bv;
    }
    __syncthreads();
    p ^= 1;
  }
}

template <bool RELU, bool RESID, bool OUTBF>
__global__ __launch_bounds__(256) void gemm_kernel(
    const u16* __restrict__ A, const u16* __restrict__ Bt,
    const float* __restrict__ bias, const float* __restrict__ resid,
    float* __restrict__ outf, u16* __restrict__ outb, int N, int K) {
  __shared__ u16 As[2][64][40];
  __shared__ u16 Bs[2][64][40];
  int m0 = blockIdx.x * 64, n0 = blockIdx.y * 64;
  f32x4 acc[2][2] = {};
  gemm_acc(A, Bt, K, m0, n0, As, Bs, acc);
  int lane = threadIdx.x & 63, wid = threadIdx.x >> 6;
  int wm = wid >> 1, wn = wid & 1;
  int g = lane >> 4, lr = lane & 15;
#pragma unroll
  for (int mi = 0; mi < 2; ++mi)
#pragma unroll
    for (int ni = 0; ni < 2; ++ni)
#pragma unroll
      for (int r = 0; r < 4; ++r) {
        int row = m0 + wm * 32 + mi * 16 + g * 4 + r;
        int col = n0 + wn * 32 + ni * 16 + lr;
        float v = acc[mi][ni][r] + bias[col];
        if (RELU) v = fmaxf(v, 0.0f);
        if (RESID) v += resid[(size_t)row * N + col];
        if (OUTBF)
          outb[(size_t)row * N + col] = f2bf(v);
        else
          outf[(size_t)row * N + col] = v;
      }
}

// QKV fused GEMM. z=0: Q row-major. z=1: K fragment layout. z=2: V^T fragment
// layout. K/V layouts are pre-XOR-swizzled (i ^= ((i>>7)&3)<<4 within each
// 1024-u16 kv64 tile) so attention can stage LDS linearly and read swizzled.
__global__ __launch_bounds__(256) void gemm_qkv(
    const u16* __restrict__ a0, const u16* __restrict__ a1, const u16* __restrict__ a2,
    const u16* __restrict__ w0, const u16* __restrict__ w1, const u16* __restrict__ w2,
    const float* __restrict__ c0, const float* __restrict__ c1, const float* __restrict__ c2,
    u16* __restrict__ Qb, u16* __restrict__ KtG, u16* __restrict__ VtG) {
  __shared__ u16 As[2][64][40];
  __shared__ u16 Bs[2][64][40];
  int z = blockIdx.z;
  const u16* A = z == 0 ? a0 : z == 1 ? a1 : a2;
  const u16* Bt = z == 0 ? w0 : z == 1 ? w1 : w2;
  const float* bias = z == 0 ? c0 : z == 1 ? c1 : c2;
  int m0 = blockIdx.x * 64, n0 = blockIdx.y * 64;
  f32x4 acc[2][2] = {};
  gemm_acc(A, Bt, D, m0, n0, As, Bs, acc);
  int lane = threadIdx.x & 63, wid = threadIdx.x >> 6;
  int wm = wid >> 1, wn = wid & 1;
  int g = lane >> 4, lr = lane & 15;
#pragma unroll
  for (int mi = 0; mi < 2; ++mi)
#pragma unroll
    for (int ni = 0; ni < 2; ++ni)
#pragma unroll
      for (int r = 0; r < 4; ++r) {
        int row = m0 + wm * 32 + mi * 16 + g * 4 + r;
        int col = n0 + wn * 32 + ni * 16 + lr;
        u16 bf = f2bf(acc[mi][ni][r] + bias[col]);
        if (z == 0) {
          Qb[(size_t)row * D + col] = bf;
        } else if (z == 1) {
          int h = col >> 4, hi2 = (lr >> 3) & 1, j = col & 7;
          int kv32 = row >> 5, lqv = row & 31;
          int I = (((kv32 * 2 + hi2) * 32) + lqv) * 8 + j;
          I ^= ((I >> 7) & 3) << 4;
          KtG[(size_t)h * 32768 + I] = bf;
        } else {
          int h = col >> 4, d = col & 15;
          int kv32 = row >> 5, g4v = (row >> 3) & 3, j = row & 7;
          int I = (((kv32 * 4 + g4v) * 16) + d) * 8 + j;
          I ^= ((I >> 7) & 3) << 4;
          VtG[(size_t)h * 32768 + I] = bf;
        }
      }
}

// ---------------- causal flash attention, split-KV (4-tile chunks) ----------------
// Block = (flat chunk f, head). chunk group g = qt>>2, nc(qt) = g+1.
// 2 waves; wave w owns q rows [qt*64 + w*32, +32).
__global__ __launch_bounds__(128) void attn_kernel(const u16* __restrict__ Qb,
                                                   const u16* __restrict__ KtG,
                                                   const u16* __restrict__ VtG,
                                                   u16* __restrict__ ctx,
                                                   u16* __restrict__ part) {
  __shared__ u16 Kl[2][1024];  // double-buffered kv64 tile (pre-swizzled layout)
  __shared__ u16 Vl[2][1024];
  __shared__ u16 Pl[2][2048];  // per-wave P, XOR-swizzled

  const int t = threadIdx.x, w = t >> 6, lane = t & 63;
  const int h = blockIdx.y;
  const int f = 143 - blockIdx.x;  // longest chunks dispatched first
  int g = (int)((sqrtf((float)(1 + 2 * f)) - 1.0f) * 0.5f);
  while (2 * (g + 1) * (g + 2) <= f) ++g;
  while (2 * g * (g + 1) > f) --g;
  const int fg = f - 2 * g * (g + 1);
  const int qt = 4 * g + fg / (g + 1);
  const int c = fg - (fg / (g + 1)) * (g + 1);
  const int t0 = 4 * c;
  const int t1 = (4 * c + 3 < qt) ? 4 * c + 3 : qt;

  const int q0w = qt * 64 + w * 32;
  const int lq = lane & 31, hi = lane >> 5;
  const int l16 = lane & 15, g4 = lane >> 4;

  short8 qf = *(const short8*)(Qb + (size_t)(q0w + lq) * D + h * DHD + hi * 8);
  const u16* Kt_h = KtG + (size_t)h * 32768;
  const u16* Vt_h = VtG + (size_t)h * 32768;

  f32x4 acc[2] = {};
  float Mrun = -1e30f, Lrun = 0.0f;

  uint4 kreg = *(const uint4*)(Kt_h + (size_t)t0 * 1024 + t * 8);
  uint4 vreg = *(const uint4*)(Vt_h + (size_t)t0 * 1024 + t * 8);
  *(uint4*)&Kl[0][t * 8] = kreg;
  *(uint4*)&Vl[0][t * 8] = vreg;
  __syncthreads();
  int pb = 0;

  for (int tt = t0; tt <= t1; ++tt) {
    if (tt < t1) {
      kreg = *(const uint4*)(Kt_h + (size_t)(tt + 1) * 1024 + t * 8);
      vreg = *(const uint4*)(Vt_h + (size_t)(tt + 1) * 1024 + t * 8);
    }
    const int kv0 = tt * 64;
    const bool v1 = (kv0 + 32) <= (q0w + 31);
    float p[2][16];

    // ---- QK^T (swapped): S^T[kv][q] ----
#pragma unroll
    for (int sx = 0; sx < 2; ++sx) {
      if (sx == 0 || v1) {
        int ko = (sx * 2 + hi) * 256 + lq * 8;
        ko ^= ((ko >> 7) & 3) << 4;
        short8 kf = *(const short8*)&Kl[pb][ko];
        f32x16 z = {};
        f32x16 st = __builtin_amdgcn_mfma_f32_32x32x16_bf16(kf, qf, z, 0, 0, 0);
        const bool needMask = (kv0 + sx * 32 + 31) > q0w;
#pragma unroll
        for (int r = 0; r < 16; ++r) {
          float tv = st[r] * C1;
          if (needMask) {
            int kv = kv0 + sx * 32 + (r & 3) + 8 * (r >> 2) + 4 * hi;
            if (kv > q0w + lq) tv = -1e30f;
          }
          p[sx][r] = tv;
        }
      }
    }

    // ---- online softmax (lane-local over kv, one cross-half exchange) ----
    float mx = p[0][0];
#pragma unroll
    for (int r = 1; r < 16; ++r) mx = fmaxf(mx, p[0][r]);
    if (v1) {
#pragma unroll
      for (int r = 0; r < 16; ++r) mx = fmaxf(mx, p[1][r]);
    }
    mx = fmaxf(mx, __shfl_xor(mx, 32));
    float Mnew = fmaxf(Mrun, mx);
    float corr = exp2f(Mrun - Mnew);
    float sum = 0.0f;
#pragma unroll
    for (int sx = 0; sx < 2; ++sx) {
      if (sx == 0 || v1) {
#pragma unroll
        for (int r = 0; r < 16; ++r) {
          float e = exp2f(p[sx][r] - Mnew);
          p[sx][r] = e;
          sum += e;
        }
      }
    }
    sum += __shfl_xor(sum, 32);
    Lrun = Lrun * corr + sum;
    Mrun = Mnew;

#pragma unroll
    for (int sq = 0; sq < 2; ++sq)
#pragma unroll
      for (int r = 0; r < 4; ++r) {
        float cc = __shfl(corr, sq * 16 + g4 * 4 + r);
        acc[sq][r] *= cc;
      }

    // ---- pack P (cvt_pk) into swizzled LDS ----
#pragma unroll
    for (int sx = 0; sx < 2; ++sx) {
      if (sx == 0 || v1) {
#pragma unroll
        for (int k = 0; k < 4; ++k) {
          unsigned int w0, w1;
          asm("v_cvt_pk_bf16_f32 %0, %1, %2" : "=v"(w0) : "v"(p[sx][4 * k]), "v"(p[sx][4 * k + 1]));
          asm("v_cvt_pk_bf16_f32 %0, %1, %2" : "=v"(w1) : "v"(p[sx][4 * k + 2]), "v"(p[sx][4 * k + 3]));
          int po = (((lq >> 4) * 2 + sx) * 4 + k) * 128 + (lq & 15) * 8 + 4 * hi;
          po ^= (k << 4);
          uint2 pv2; pv2.x = w0; pv2.y = w1;
          *(uint2*)&Pl[w][po] = pv2;
        }
      }
    }

    // ---- PV ----
#pragma unroll
    for (int sx = 0; sx < 2; ++sx) {
      if (sx == 0 || v1) {
        int vo = ((sx * 4 + g4) * 128 + l16 * 8) ^ (g4 << 4);
        short8 vf = *(const short8*)&Vl[pb][vo];
#pragma unroll
        for (int sq = 0; sq < 2; ++sq) {
          int po = (((sq * 2 + sx) * 4 + g4) * 128 + l16 * 8) ^ (g4 << 4);
          short8 pf = *(const short8*)&Pl[w][po];
          acc[sq] = __builtin_amdgcn_mfma_f32_16x16x32_bf16(pf, vf, acc[sq], 0, 0, 0);
        }
      }
    }

    if (tt < t1) {
      *(uint4*)&Kl[pb ^ 1][t * 8] = kreg;
      *(uint4*)&Vl[pb ^ 1][t * 8] = vreg;
    }
    __syncthreads();
    pb ^= 1;
  }

  if (g == 0) {  // single chunk: direct output
#pragma unroll
    for (int sq = 0; sq < 2; ++sq)
#pragma unroll
      for (int r = 0; r < 4; ++r) {
        int qlr = sq * 16 + g4 * 4 + r;
        float lv = __shfl(Lrun, qlr);
        ctx[(size_t)(q0w + qlr) * D + h * DHD + l16] = f2bf(acc[sq][r] / lv);
      }
  } else {
    // partial row: 20 u16 = [m f32][l f32][16 x bf16 O]
    const int pslot = 2 * g * (g + 1) + (qt - 4 * g) * (g + 1) - 4 + c;
    u16* ps = part + ((size_t)(h * 140 + pslot)) * 1280;
#pragma unroll
    for (int sq = 0; sq < 2; ++sq)
#pragma unroll
      for (int r = 0; r < 4; ++r) {
        int qlocal = w * 32 + sq * 16 + g4 * 4 + r;
        ps[qlocal * 20 + 4 + l16] = f2bf(acc[sq][r]);
      }
    if (hi == 0) {
      int ql = w * 32 + lq;
      *(float*)(ps + ql * 20) = Mrun;
      *(float*)(ps + ql * 20 + 2) = Lrun;
    }
  }
}

// ---------------- merge split-KV partials (qt >= 4) ----------------
__global__ __launch_bounds__(64) void attn_merge(const u16* __restrict__ part,
                                                 u16* __restrict__ ctx) {
  int qt = 4 + blockIdx.x, h = blockIdx.y, tq = threadIdx.x;
  int g = qt >> 2, nc = g + 1;
  int base = 2 * g * (g + 1) + (qt - 4 * g) * (g + 1) - 4;
  const u16* bp = part + ((size_t)(h * 140 + base)) * 1280 + tq * 20;
  float M = -1e30f;
  for (int c = 0; c < nc; ++c) M = fmaxf(M, *(const float*)(bp + (size_t)c * 1280));
  float L = 0.0f;
  float o[16];
#pragma unroll
  for (int d = 0; d < 16; ++d) o[d] = 0.0f;
  for (int c = 0; c < nc; ++c) {
    const u16* pr = bp + (size_t)c * 1280;
    float m = *(const float*)pr;
    float l = *(const float*)(pr + 2);
    float sc = exp2f(m - M);
    L += l * sc;
#pragma unroll
    for (int k = 0; k < 4; ++k) {
      us4 ov = *(const us4*)(pr + 4 + 4 * k);
#pragma unroll
      for (int j = 0; j < 4; ++j) o[4 * k + j] += bf2f(ov[j]) * sc;
    }
  }
  float inv = 1.0f / L;
  int q = qt * 64 + tq;
  u16* op = ctx + (size_t)q * D + h * DHD;
#pragma unroll
  for (int k = 0; k < 4; ++k) {
    us4 pk;
#pragma unroll
    for (int j = 0; j < 4; ++j) pk[j] = f2bf(o[4 * k + j] * inv);
    *(us4*)(op + 4 * k) = pk;
  }
}

// ---------------- launcher ----------------
extern "C" void kernel_launch(void* const* d_in, const int* in_sizes, int n_in,
                              void* d_out, int out_size, void* d_ws, size_t ws_size,
                              hipStream_t stream) {
  const float* x = (const float*)d_in[0];
  const float* ln0_g = (const float*)d_in[1];
  const float* ln0_b = (const float*)d_in[2];
  const float* lnq_g = (const float*)d_in[3];
  const float* lnq_b = (const float*)d_in[4];
  const float* lnk_g = (const float*)d_in[5];
  const float* lnk_b = (const float*)d_in[6];
  const float* lnv_g = (const float*)d_in[7];
  const float* lnv_b = (const float*)d_in[8];
  const float* Wq = (const float*)d_in[9];
  const float* bq = (const float*)d_in[10];
  const float* Wk = (const float*)d_in[11];
  const float* bk = (const float*)d_in[12];
  const float* Wv = (const float*)d_in[13];
  const float* bv = (const float*)d_in[14];
  const float* Wo = (const float*)d_in[15];
  const float* bo = (const float*)d_in[16];
  const float* lnf_g = (const float*)d_in[17];
  const float* lnf_b = (const float*)d_in[18];
  const float* W1 = (const float*)d_in[19];
  const float* b1 = (const float*)d_in[20];
  const float* W2 = (const float*)d_in[21];
  const float* b2 = (const float*)d_in[22];

  char* wsp = (char*)d_ws;
  size_t off = 0;
  auto alloc = [&](size_t bytes) -> void* {
    void* p = wsp + off;
    off += (bytes + 255) & ~(size_t)255;
    return p;
  };
  // ---- fixed region (live across attention) ----
  float* xn = (float*)alloc((size_t)S * D * 4);
  u16* Qb = (u16*)alloc((size_t)S * D * 2);
  u16* ctx = (u16*)alloc((size_t)S * D * 2);
  u16* KtG = (u16*)alloc((size_t)S * D * 2);
  u16* VtG = (u16*)alloc((size_t)S * D * 2);
  u16* WqT = (u16*)alloc((size_t)D * D * 2);
  u16* WkT = (u16*)alloc((size_t)D * D * 2);
  u16* WvT = (u16*)alloc((size_t)D * D * 2);
  u16* WoT = (u16*)alloc((size_t)D * D * 2);
  u16* W1T = (u16*)alloc((size_t)D * DFF * 2);
  u16* W2T = (u16*)alloc((size_t)DFF * D * 2);
  // ---- multiplexed region B (phases don't overlap in stream order) ----
  char* regB = (char*)alloc((size_t)15 * 1024 * 1024);
  u16* qin = (u16*)regB;                                  // phase 1
  u16* kin = (u16*)(regB + (size_t)S * D * 2);
  u16* vin = (u16*)(regB + (size_t)S * D * 4);
  u16* part = (u16*)regB;                                 // phase 2 (11.47MB)
  float* outb = (float*)regB;                             // phase 3
  u16* lnf = (u16*)(regB + (size_t)S * D * 4);
  u16* hbuf = (u16*)(regB + (size_t)S * D * 6);

  dim3 tb(32, 8);
  transpose4<<<dim3(D / 32, D / 32, 4), tb, 0, stream>>>(Wq, Wk, Wv, Wo, WqT, WkT, WvT, WoT);
  transpose_bf16<<<dim3(DFF / 32, D / 32), tb, 0, stream>>>(W1, W1T, D, DFF);
  transpose_bf16<<<dim3(D / 32, DFF / 32), tb, 0, stream>>>(W2, W2T, DFF, D);

  ln0_kernel<<<S, 256, 0, stream>>>(x, ln0_g, ln0_b, lnq_g, lnq_b, lnk_g, lnk_b,
                                    lnv_g, lnv_b, xn, qin, kin, vin);

  gemm_qkv<<<dim3(S / 64, D / 64, 3), 256, 0, stream>>>(
      qin, kin, vin, WqT, WkT, WvT, bq, bk, bv, Qb, KtG, VtG);

  attn_kernel<<<dim3(144, NH), 128, 0, stream>>>(Qb, KtG, VtG, ctx, part);

  attn_merge<<<dim3(28, NH), 64, 0, stream>>>(part, ctx);

  gemm_kernel<false, true, false><<<dim3(S / 64, D / 64), 256, 0, stream>>>(
      ctx, WoT, bo, xn, outb, nullptr, D, D);

  ln2_kernel<<<S, 256, 0, stream>>>(outb, lnf_g, lnf_b, lnf);

  gemm_kernel<true, false, true><<<dim3(S / 64, DFF / 64), 256, 0, stream>>>(
      lnf, W1T, b1, nullptr, nullptr, hbuf, DFF, D);

  gemm_kernel<true, true, false><<<dim3(S / 64, D / 64), 256, 0, stream>>>(
      hbuf, W2T, b2, outb, (float*)d_out, nullptr, D, DFF);

  (void)in_sizes; (void)n_in; (void)out_size; (void)ws_size;
}

// Round 5
// 109.223 us; speedup vs baseline: 1.6432x; 1.0459x over previous
//
#include <hip/hip_runtime.h>

#define S 2048
#define D 512
#define NH 32
#define DHD 16
#define DFF 1024
#define EPS 1e-5f
#define C1 0.36067376022224085f  // (1/sqrt(16)) * log2(e), folded into Q

typedef unsigned short u16;
typedef __attribute__((ext_vector_type(8))) short short8;
typedef __attribute__((ext_vector_type(4))) float f32x4;
typedef __attribute__((ext_vector_type(16))) float f32x16;
typedef __attribute__((ext_vector_type(4))) unsigned short us4;

#define GL_LDS(gsrc, ldst)                                                   \
  __builtin_amdgcn_global_load_lds(                                          \
      (const __attribute__((address_space(1))) unsigned int*)(gsrc),         \
      (__attribute__((address_space(3))) unsigned int*)(ldst), 16, 0, 0)

static __device__ __forceinline__ u16 f2bf(float f) {
  union { float f; unsigned int i; } c; c.f = f;
  unsigned int x = c.i;
  return (u16)((x + 0x7fffu + ((x >> 16) & 1u)) >> 16);
}
static __device__ __forceinline__ float bf2f(u16 v) {
  union { unsigned int i; float f; } c; c.i = ((unsigned int)v) << 16;
  return c.f;
}

static __device__ __forceinline__ float tmax16(const float* p) {
  float a0 = fmaxf(p[0], p[1]), a1 = fmaxf(p[2], p[3]);
  float a2 = fmaxf(p[4], p[5]), a3 = fmaxf(p[6], p[7]);
  float a4 = fmaxf(p[8], p[9]), a5 = fmaxf(p[10], p[11]);
  float a6 = fmaxf(p[12], p[13]), a7 = fmaxf(p[14], p[15]);
  float b0 = fmaxf(a0, a1), b1 = fmaxf(a2, a3);
  float b2 = fmaxf(a4, a5), b3 = fmaxf(a6, a7);
  return fmaxf(fmaxf(b0, b1), fmaxf(b2, b3));
}
static __device__ __forceinline__ float tsum16(const float* p) {
  float a0 = p[0] + p[1], a1 = p[2] + p[3], a2 = p[4] + p[5], a3 = p[6] + p[7];
  float a4 = p[8] + p[9], a5 = p[10] + p[11], a6 = p[12] + p[13], a7 = p[14] + p[15];
  float b0 = a0 + a1, b1 = a2 + a3, b2 = a4 + a5, b3 = a6 + a7;
  return (b0 + b1) + (b2 + b3);
}

static __device__ __forceinline__ void block_reduce2(float& a, float& b, float* sm, int t) {
#pragma unroll
  for (int m = 1; m <= 32; m <<= 1) {
    a += __shfl_xor(a, m);
    b += __shfl_xor(b, m);
  }
  int w = t >> 6;
  if ((t & 63) == 0) { sm[w] = a; sm[4 + w] = b; }
  __syncthreads();
  a = sm[0] + sm[1] + sm[2] + sm[3];
  b = sm[4] + sm[5] + sm[6] + sm[7];
  __syncthreads();
}

// ---------------- LN kernels ----------------
__global__ __launch_bounds__(256) void ln0_kernel(
    const float* __restrict__ x,
    const float* __restrict__ g0, const float* __restrict__ b0,
    const float* __restrict__ gq, const float* __restrict__ bq,
    const float* __restrict__ gk, const float* __restrict__ bk,
    const float* __restrict__ gv, const float* __restrict__ bv,
    float* __restrict__ xn, u16* __restrict__ qin, u16* __restrict__ kin,
    u16* __restrict__ vin) {
  __shared__ float red[8];
  int row = blockIdx.x, t = threadIdx.x;
  const float* xr = x + (size_t)row * D;
  float a0 = xr[t], a1 = xr[t + 256];
  float s = a0 + a1, ss = a0 * a0 + a1 * a1;
  block_reduce2(s, ss, red, t);
  float mean = s * (1.0f / D);
  float var = ss * (1.0f / D) - mean * mean;
  float rs = rsqrtf(var + EPS);
  float y0 = (a0 - mean) * rs * g0[t] + b0[t];
  float y1 = (a1 - mean) * rs * g0[t + 256] + b0[t + 256];
  size_t o = (size_t)row * D + t;
  xn[o] = y0;
  xn[o + 256] = y1;
  float s2 = y0 + y1, ss2 = y0 * y0 + y1 * y1;
  block_reduce2(s2, ss2, red, t);
  float m2 = s2 * (1.0f / D);
  float v2 = ss2 * (1.0f / D) - m2 * m2;
  float rs2 = rsqrtf(v2 + EPS);
  float c0 = (y0 - m2) * rs2, c1 = (y1 - m2) * rs2;
  qin[o] = f2bf(c0 * gq[t] + bq[t]);
  qin[o + 256] = f2bf(c1 * gq[t + 256] + bq[t + 256]);
  kin[o] = f2bf(c0 * gk[t] + bk[t]);
  kin[o + 256] = f2bf(c1 * gk[t + 256] + bk[t + 256]);
  vin[o] = f2bf(c0 * gv[t] + bv[t]);
  vin[o + 256] = f2bf(c1 * gv[t + 256] + bv[t + 256]);
}

__global__ __launch_bounds__(256) void ln2_kernel(
    const float* __restrict__ in, const float* __restrict__ g,
    const float* __restrict__ b, u16* __restrict__ out) {
  __shared__ float red[8];
  int row = blockIdx.x, t = threadIdx.x;
  const float* xr = in + (size_t)row * D;
  float a0 = xr[t], a1 = xr[t + 256];
  float s = a0 + a1, ss = a0 * a0 + a1 * a1;
  block_reduce2(s, ss, red, t);
  float mean = s * (1.0f / D);
  float var = ss * (1.0f / D) - mean * mean;
  float rs = rsqrtf(var + EPS);
  size_t o = (size_t)row * D + t;
  out[o] = f2bf((a0 - mean) * rs * g[t] + b[t]);
  out[o + 256] = f2bf((a1 - mean) * rs * g[t + 256] + b[t + 256]);
}

// ---------------- weight transposes fp32 -> bf16 ----------------
static __device__ __forceinline__ void transpose_core(const float* __restrict__ W,
                                                      u16* __restrict__ Wt, int K, int N,
                                                      float (*tile)[33]) {
  int n0 = blockIdx.x * 32, k0 = blockIdx.y * 32;
  int tx = threadIdx.x, ty = threadIdx.y;  // (32,8)
#pragma unroll
  for (int i = 0; i < 4; ++i)
    tile[ty + 8 * i][tx] = W[(size_t)(k0 + ty + 8 * i) * N + n0 + tx];
  __syncthreads();
#pragma unroll
  for (int i = 0; i < 4; ++i)
    Wt[(size_t)(n0 + ty + 8 * i) * K + k0 + tx] = f2bf(tile[tx][ty + 8 * i]);
}

__global__ void transpose4(const float* __restrict__ W0, const float* __restrict__ W1,
                           const float* __restrict__ W2, const float* __restrict__ W3,
                           u16* __restrict__ T0, u16* __restrict__ T1,
                           u16* __restrict__ T2, u16* __restrict__ T3) {
  __shared__ float tile[32][33];
  int z = blockIdx.z;
  const float* W = z == 0 ? W0 : z == 1 ? W1 : z == 2 ? W2 : W3;
  u16* T = z == 0 ? T0 : z == 1 ? T1 : z == 2 ? T2 : T3;
  transpose_core(W, T, D, D, tile);
}

__global__ void transpose_bf16(const float* __restrict__ W, u16* __restrict__ Wt,
                               int K, int N) {
  __shared__ float tile[32][33];
  transpose_core(W, Wt, K, N, tile);
}

// ---------------- GEMM: 128x64 tile, BK=64, global_load_lds + swizzle ----------------
// LDS layout: rows of 64 u16 (8 slots of 8 u16); slot stored = logical_slot ^ (row&7).
// Staged via global_load_lds with pre-swizzled SOURCE column; read with swizzled slot.
static __device__ __forceinline__ void gemm_stage(
    const u16* __restrict__ A, const u16* __restrict__ Bt, int K,
    int m0, int n0, int kk, u16* As, u16* Bs, int w, int lane) {
  int r8 = lane >> 3;
  int c8 = ((lane & 7) ^ r8) * 8;
#pragma unroll
  for (int j = 0; j < 4; ++j) {
    int chunk = j * 4 + w;
    GL_LDS(A + (size_t)(m0 + chunk * 8 + r8) * K + kk + c8, As + chunk * 512);
  }
#pragma unroll
  for (int j = 0; j < 2; ++j) {
    int chunk = j * 4 + w;
    GL_LDS(Bt + (size_t)(n0 + chunk * 8 + r8) * K + kk + c8, Bs + chunk * 512);
  }
}

static __device__ __forceinline__ void gemm_acc128(
    const u16* __restrict__ A, const u16* __restrict__ Bt, int K, int m0, int n0,
    u16 (*As)[8192], u16 (*Bs)[4096], f32x4 acc[4][2]) {
  int t = threadIdx.x, w = t >> 6, lane = t & 63;
  int wm = w >> 1, wn = w & 1;
  int l16 = lane & 15, g4 = lane >> 4;
  gemm_stage(A, Bt, K, m0, n0, 0, As[0], Bs[0], w, lane);
  __syncthreads();
  int pb = 0;
  for (int kk = 0; kk < K; kk += 64) {
    if (kk + 64 < K)
      gemm_stage(A, Bt, K, m0, n0, kk + 64, As[pb ^ 1], Bs[pb ^ 1], w, lane);
#pragma unroll
    for (int ks = 0; ks < 2; ++ks) {
      short8 af[4], bf[2];
#pragma unroll
      for (int mi = 0; mi < 4; ++mi) {
        int row = wm * 64 + mi * 16 + l16;
        af[mi] = *(const short8*)&As[pb][row * 64 + (((ks * 4 + g4) ^ (l16 & 7)) * 8)];
      }
#pragma unroll
      for (int ni = 0; ni < 2; ++ni) {
        int row = wn * 32 + ni * 16 + l16;
        bf[ni] = *(const short8*)&Bs[pb][row * 64 + (((ks * 4 + g4) ^ (l16 & 7)) * 8)];
      }
#pragma unroll
      for (int mi = 0; mi < 4; ++mi)
#pragma unroll
        for (int ni = 0; ni < 2; ++ni)
          acc[mi][ni] = __builtin_amdgcn_mfma_f32_16x16x32_bf16(
              af[mi], bf[ni], acc[mi][ni], 0, 0, 0);
    }
    __syncthreads();
    pb ^= 1;
  }
}

template <bool RELU, bool RESID, bool OUTBF>
__global__ __launch_bounds__(256) void gemm_kernel(
    const u16* __restrict__ A, const u16* __restrict__ Bt,
    const float* __restrict__ bias, const float* __restrict__ resid,
    float* __restrict__ outf, u16* __restrict__ outb, int N, int K) {
  __shared__ u16 As[2][8192];
  __shared__ u16 Bs[2][4096];
  int m0 = blockIdx.x * 128, n0 = blockIdx.y * 64;
  f32x4 acc[4][2] = {};
  gemm_acc128(A, Bt, K, m0, n0, As, Bs, acc);
  int t = threadIdx.x, w = t >> 6, lane = t & 63;
  int wm = w >> 1, wn = w & 1;
  int l16 = lane & 15, g4 = lane >> 4;
#pragma unroll
  for (int mi = 0; mi < 4; ++mi)
#pragma unroll
    for (int ni = 0; ni < 2; ++ni)
#pragma unroll
      for (int r = 0; r < 4; ++r) {
        int row = m0 + wm * 64 + mi * 16 + g4 * 4 + r;
        int col = n0 + wn * 32 + ni * 16 + l16;
        float v = acc[mi][ni][r] + bias[col];
        if (RELU) v = fmaxf(v, 0.0f);
        if (RESID) v += resid[(size_t)row * N + col];
        if (OUTBF)
          outb[(size_t)row * N + col] = f2bf(v);
        else
          outf[(size_t)row * N + col] = v;
      }
}

// QKV fused GEMM. z=0: Q row-major (scaled by C1). z=1: K fragment layout.
// z=2: V^T fragment layout (attention reads fragments directly from global).
__global__ __launch_bounds__(256) void gemm_qkv(
    const u16* __restrict__ a0, const u16* __restrict__ a1, const u16* __restrict__ a2,
    const u16* __restrict__ w0, const u16* __restrict__ w1, const u16* __restrict__ w2,
    const float* __restrict__ c0, const float* __restrict__ c1, const float* __restrict__ c2,
    u16* __restrict__ Qb, u16* __restrict__ KtG, u16* __restrict__ VtG) {
  __shared__ u16 As[2][8192];
  __shared__ u16 Bs[2][4096];
  int z = blockIdx.z;
  const u16* A = z == 0 ? a0 : z == 1 ? a1 : a2;
  const u16* Bt = z == 0 ? w0 : z == 1 ? w1 : w2;
  const float* bias = z == 0 ? c0 : z == 1 ? c1 : c2;
  int m0 = blockIdx.x * 128, n0 = blockIdx.y * 64;
  f32x4 acc[4][2] = {};
  gemm_acc128(A, Bt, D, m0, n0, As, Bs, acc);
  int t = threadIdx.x, w = t >> 6, lane = t & 63;
  int wm = w >> 1, wn = w & 1;
  int l16 = lane & 15, g4 = lane >> 4;
#pragma unroll
  for (int mi = 0; mi < 4; ++mi)
#pragma unroll
    for (int ni = 0; ni < 2; ++ni)
#pragma unroll
      for (int r = 0; r < 4; ++r) {
        int row = m0 + wm * 64 + mi * 16 + g4 * 4 + r;
        int col = n0 + wn * 32 + ni * 16 + l16;
        float v = acc[mi][ni][r] + bias[col];
        if (z == 0) {
          Qb[(size_t)row * D + col] = f2bf(v * C1);
        } else if (z == 1) {
          u16 bf = f2bf(v);
          int h = col >> 4, d = col & 15;
          int I = (((row >> 5) * 2 + (d >> 3)) * 32 + (row & 31)) * 8 + (d & 7);
          KtG[(size_t)h * 32768 + I] = bf;
        } else {
          u16 bf = f2bf(v);
          int h = col >> 4, d = col & 15;
          int I = (((row >> 5) * 4 + ((row >> 3) & 3)) * 16 + d) * 8 + (row & 7);
          VtG[(size_t)h * 32768 + I] = bf;
        }
      }
}

// ---------------- causal flash attention, split-KV, barrier-free ----------------
// Block = (flat chunk f, head); chunk = up to 4 kv64 tiles. 2 independent waves;
// wave w owns q rows [qt*64 + w*32, +32). K/V fragments read directly from
// global (L2-resident); P round-trips through per-wave swizzled LDS.
__global__ __launch_bounds__(128) void attn_kernel(const u16* __restrict__ Qb,
                                                   const u16* __restrict__ KtG,
                                                   const u16* __restrict__ VtG,
                                                   u16* __restrict__ ctx,
                                                   u16* __restrict__ part) {
  __shared__ u16 Pl[2][2048];

  const int t = threadIdx.x, w = t >> 6, lane = t & 63;
  const int h = blockIdx.y;
  const int f = 143 - blockIdx.x;  // longest chunks dispatched first
  int g = (int)((sqrtf((float)(1 + 2 * f)) - 1.0f) * 0.5f);
  while (2 * (g + 1) * (g + 2) <= f) ++g;
  while (2 * g * (g + 1) > f) --g;
  const int fg = f - 2 * g * (g + 1);
  const int qt = 4 * g + fg / (g + 1);
  const int c = fg - (fg / (g + 1)) * (g + 1);
  const int t0 = 4 * c;
  const int t1 = (4 * c + 3 < qt) ? 4 * c + 3 : qt;

  const int q0w = qt * 64 + w * 32;
  const int lq = lane & 31, hi = lane >> 5;
  const int l16 = lane & 15, g4 = lane >> 4;

  short8 qf = *(const short8*)(Qb + (size_t)(q0w + lq) * D + h * DHD + hi * 8);
  const u16* kp = KtG + (size_t)h * 32768 + (size_t)t0 * 1024 + hi * 256 + lq * 8;
  const u16* vp = VtG + (size_t)h * 32768 + (size_t)t0 * 1024 + g4 * 128 + l16 * 8;

  f32x4 acc[2] = {};
  float Mrun = -1e30f, Lrun = 0.0f;

  short8 kf0 = *(const short8*)kp;
  short8 kf1 = *(const short8*)(kp + 512);
  short8 vf0 = *(const short8*)vp;
  short8 vf1 = *(const short8*)(vp + 512);

  u16* Pw = &Pl[w][0];
  const int pwr = (lq >> 4) * 1024 + (lq & 15) * 8 + 4 * hi;  // P write base
  const int prd = g4 * 128 + l16 * 8;                          // P read base

  for (int tt = t0; tt <= t1; ++tt) {
    const int kv0 = tt * 64;
    const bool v1 = (kv0 + 32) <= (q0w + 31);
    f32x16 z = {};
    f32x16 st0 = __builtin_amdgcn_mfma_f32_32x32x16_bf16(kf0, qf, z, 0, 0, 0);
    f32x16 st1 = z;
    if (v1) st1 = __builtin_amdgcn_mfma_f32_32x32x16_bf16(kf1, qf, z, 0, 0, 0);

    short8 nk0, nk1, nv0, nv1;
    const bool more = (tt < t1);
    if (more) {  // issue next-tile loads early; they hide under softmax
      kp += 1024; vp += 1024;
      nk0 = *(const short8*)kp;
      nk1 = *(const short8*)(kp + 512);
      nv0 = *(const short8*)vp;
      nv1 = *(const short8*)(vp + 512);
    }

    // ---- mask (cheap per-lane threshold) ----
    float p0[16], p1[16];
    const int thr0 = q0w + lq - kv0 - 4 * hi;
    if (kv0 + 31 > q0w) {
#pragma unroll
      for (int r = 0; r < 16; ++r) {
        const int rc = (r & 3) + 8 * (r >> 2);
        p0[r] = (rc > thr0) ? -1e30f : st0[r];
      }
    } else {
#pragma unroll
      for (int r = 0; r < 16; ++r) p0[r] = st0[r];
    }
    if (v1) {
      const int thr1 = thr0 - 32;
      if (kv0 + 63 > q0w) {
#pragma unroll
        for (int r = 0; r < 16; ++r) {
          const int rc = (r & 3) + 8 * (r >> 2);
          p1[r] = (rc > thr1) ? -1e30f : st1[r];
        }
      } else {
#pragma unroll
        for (int r = 0; r < 16; ++r) p1[r] = st1[r];
      }
    }

    // ---- online softmax (tree reductions, one cross-half exchange) ----
    float mx = tmax16(p0);
    if (v1) mx = fmaxf(mx, tmax16(p1));
    mx = fmaxf(mx, __shfl_xor(mx, 32));
    float Mnew = fmaxf(Mrun, mx);
    float corr = exp2f(Mrun - Mnew);
#pragma unroll
    for (int r = 0; r < 16; ++r) p0[r] = exp2f(p0[r] - Mnew);
    float sum = tsum16(p0);
    if (v1) {
#pragma unroll
      for (int r = 0; r < 16; ++r) p1[r] = exp2f(p1[r] - Mnew);
      sum += tsum16(p1);
    }
    sum += __shfl_xor(sum, 32);
    Lrun = Lrun * corr + sum;
    Mrun = Mnew;

#pragma unroll
    for (int sq = 0; sq < 2; ++sq)
#pragma unroll
      for (int r = 0; r < 4; ++r) {
        float cc = __shfl(corr, sq * 16 + g4 * 4 + r);
        acc[sq][r] *= cc;
      }

    // ---- pack P (cvt_pk) into swizzled per-wave LDS ----
#pragma unroll
    for (int k = 0; k < 4; ++k) {
      unsigned int w0, w1;
      asm("v_cvt_pk_bf16_f32 %0, %1, %2" : "=v"(w0) : "v"(p0[4 * k]), "v"(p0[4 * k + 1]));
      asm("v_cvt_pk_bf16_f32 %0, %1, %2" : "=v"(w1) : "v"(p0[4 * k + 2]), "v"(p0[4 * k + 3]));
      uint2 pv; pv.x = w0; pv.y = w1;
      *(uint2*)&Pw[(pwr + k * 128) ^ (k << 4)] = pv;
    }
    if (v1) {
#pragma unroll
      for (int k = 0; k < 4; ++k) {
        unsigned int w0, w1;
        asm("v_cvt_pk_bf16_f32 %0, %1, %2" : "=v"(w0) : "v"(p1[4 * k]), "v"(p1[4 * k + 1]));
        asm("v_cvt_pk_bf16_f32 %0, %1, %2" : "=v"(w1) : "v"(p1[4 * k + 2]), "v"(p1[4 * k + 3]));
        uint2 pv; pv.x = w0; pv.y = w1;
        *(uint2*)&Pw[(pwr + 512 + k * 128) ^ (k << 4)] = pv;
      }
    }

    // ---- PV (V fragments live in registers) ----
#pragma unroll
    for (int sx = 0; sx < 2; ++sx) {
      if (sx == 0 || v1) {
        short8 vf = sx ? vf1 : vf0;
#pragma unroll
        for (int sq = 0; sq < 2; ++sq) {
          short8 pf = *(const short8*)&Pw[(sq * 1024 + sx * 512 + prd) ^ (g4 << 4)];
          acc[sq] = __builtin_amdgcn_mfma_f32_16x16x32_bf16(pf, vf, acc[sq], 0, 0, 0);
        }
      }
    }

    if (more) { kf0 = nk0; kf1 = nk1; vf0 = nv0; vf1 = nv1; }
  }

  if (g == 0) {  // single chunk: direct output
#pragma unroll
    for (int sq = 0; sq < 2; ++sq)
#pragma unroll
      for (int r = 0; r < 4; ++r) {
        int qlr = sq * 16 + g4 * 4 + r;
        float lv = __shfl(Lrun, qlr);
        ctx[(size_t)(q0w + qlr) * D + h * DHD + l16] = f2bf(acc[sq][r] / lv);
      }
  } else {
    // partial row: 20 u16 = [m f32][l f32][16 x bf16 O]
    const int pslot = 2 * g * (g + 1) + (qt - 4 * g) * (g + 1) - 4 + c;
    u16* ps = part + ((size_t)(h * 140 + pslot)) * 1280;
#pragma unroll
    for (int sq = 0; sq < 2; ++sq)
#pragma unroll
      for (int r = 0; r < 4; ++r) {
        int qlocal = w * 32 + sq * 16 + g4 * 4 + r;
        ps[qlocal * 20 + 4 + l16] = f2bf(acc[sq][r]);
      }
    if (hi == 0) {
      int ql = w * 32 + lq;
      *(float*)(ps + ql * 20) = Mrun;
      *(float*)(ps + ql * 20 + 2) = Lrun;
    }
  }
}

// ---------------- merge split-KV partials (qt >= 4) ----------------
__global__ __launch_bounds__(64) void attn_merge(const u16* __restrict__ part,
                                                 u16* __restrict__ ctx) {
  int qt = 4 + blockIdx.x, h = blockIdx.y, tq = threadIdx.x;
  int g = qt >> 2, nc = g + 1;
  int base = 2 * g * (g + 1) + (qt - 4 * g) * (g + 1) - 4;
  const u16* bp = part + ((size_t)(h * 140 + base)) * 1280 + tq * 20;
  float M = -1e30f;
  for (int c = 0; c < nc; ++c) M = fmaxf(M, *(const float*)(bp + (size_t)c * 1280));
  float L = 0.0f;
  float o[16];
#pragma unroll
  for (int d = 0; d < 16; ++d) o[d] = 0.0f;
  for (int c = 0; c < nc; ++c) {
    const u16* pr = bp + (size_t)c * 1280;
    float m = *(const float*)pr;
    float l = *(const float*)(pr + 2);
    float sc = exp2f(m - M);
    L += l * sc;
#pragma unroll
    for (int k = 0; k < 4; ++k) {
      us4 ov = *(const us4*)(pr + 4 + 4 * k);
#pragma unroll
      for (int j = 0; j < 4; ++j) o[4 * k + j] += bf2f(ov[j]) * sc;
    }
  }
  float inv = 1.0f / L;
  int q = qt * 64 + tq;
  u16* op = ctx + (size_t)q * D + h * DHD;
#pragma unroll
  for (int k = 0; k < 4; ++k) {
    us4 pk;
#pragma unroll
    for (int j = 0; j < 4; ++j) pk[j] = f2bf(o[4 * k + j] * inv);
    *(us4*)(op + 4 * k) = pk;
  }
}

// ---------------- launcher ----------------
extern "C" void kernel_launch(void* const* d_in, const int* in_sizes, int n_in,
                              void* d_out, int out_size, void* d_ws, size_t ws_size,
                              hipStream_t stream) {
  const float* x = (const float*)d_in[0];
  const float* ln0_g = (const float*)d_in[1];
  const float* ln0_b = (const float*)d_in[2];
  const float* lnq_g = (const float*)d_in[3];
  const float* lnq_b = (const float*)d_in[4];
  const float* lnk_g = (const float*)d_in[5];
  const float* lnk_b = (const float*)d_in[6];
  const float* lnv_g = (const float*)d_in[7];
  const float* lnv_b = (const float*)d_in[8];
  const float* Wq = (const float*)d_in[9];
  const float* bq = (const float*)d_in[10];
  const float* Wk = (const float*)d_in[11];
  const float* bk = (const float*)d_in[12];
  const float* Wv = (const float*)d_in[13];
  const float* bv = (const float*)d_in[14];
  const float* Wo = (const float*)d_in[15];
  const float* bo = (const float*)d_in[16];
  const float* lnf_g = (const float*)d_in[17];
  const float* lnf_b = (const float*)d_in[18];
  const float* W1 = (const float*)d_in[19];
  const float* b1 = (const float*)d_in[20];
  const float* W2 = (const float*)d_in[21];
  const float* b2 = (const float*)d_in[22];

  char* wsp = (char*)d_ws;
  size_t off = 0;
  auto alloc = [&](size_t bytes) -> void* {
    void* p = wsp + off;
    off += (bytes + 255) & ~(size_t)255;
    return p;
  };
  // ---- fixed region (live across attention) ----
  float* xn = (float*)alloc((size_t)S * D * 4);
  u16* Qb = (u16*)alloc((size_t)S * D * 2);
  u16* ctx = (u16*)alloc((size_t)S * D * 2);
  u16* KtG = (u16*)alloc((size_t)S * D * 2);
  u16* VtG = (u16*)alloc((size_t)S * D * 2);
  u16* WqT = (u16*)alloc((size_t)D * D * 2);
  u16* WkT = (u16*)alloc((size_t)D * D * 2);
  u16* WvT = (u16*)alloc((size_t)D * D * 2);
  u16* WoT = (u16*)alloc((size_t)D * D * 2);
  u16* W1T = (u16*)alloc((size_t)D * DFF * 2);
  u16* W2T = (u16*)alloc((size_t)DFF * D * 2);
  // ---- multiplexed region B (phases don't overlap in stream order) ----
  char* regB = (char*)alloc((size_t)15 * 1024 * 1024);
  u16* qin = (u16*)regB;                                  // phase 1
  u16* kin = (u16*)(regB + (size_t)S * D * 2);
  u16* vin = (u16*)(regB + (size_t)S * D * 4);
  u16* part = (u16*)regB;                                 // phase 2 (11.47MB)
  float* outb = (float*)regB;                             // phase 3
  u16* lnf = (u16*)(regB + (size_t)S * D * 4);
  u16* hbuf = (u16*)(regB + (size_t)S * D * 6);

  dim3 tb(32, 8);
  transpose4<<<dim3(D / 32, D / 32, 4), tb, 0, stream>>>(Wq, Wk, Wv, Wo, WqT, WkT, WvT, WoT);
  transpose_bf16<<<dim3(DFF / 32, D / 32), tb, 0, stream>>>(W1, W1T, D, DFF);
  transpose_bf16<<<dim3(D / 32, DFF / 32), tb, 0, stream>>>(W2, W2T, DFF, D);

  ln0_kernel<<<S, 256, 0, stream>>>(x, ln0_g, ln0_b, lnq_g, lnq_b, lnk_g, lnk_b,
                                    lnv_g, lnv_b, xn, qin, kin, vin);

  gemm_qkv<<<dim3(S / 128, D / 64, 3), 256, 0, stream>>>(
      qin, kin, vin, WqT, WkT, WvT, bq, bk, bv, Qb, KtG, VtG);

  attn_kernel<<<dim3(144, NH), 128, 0, stream>>>(Qb, KtG, VtG, ctx, part);

  attn_merge<<<dim3(28, NH), 64, 0, stream>>>(part, ctx);

  gemm_kernel<false, true, false><<<dim3(S / 128, D / 64), 256, 0, stream>>>(
      ctx, WoT, bo, xn, outb, nullptr, D, D);

  ln2_kernel<<<S, 256, 0, stream>>>(outb, lnf_g, lnf_b, lnf);

  gemm_kernel<true, false, true><<<dim3(S / 128, DFF / 64), 256, 0, stream>>>(
      lnf, W1T, b1, nullptr, nullptr, hbuf, DFF, D);

  gemm_kernel<true, true, false><<<dim3(S / 128, D / 64), 256, 0, stream>>>(
      hbuf, W2T, b2, outb, (float*)d_out, nullptr, D, DFF);

  (void)in_sizes; (void)n_in; (void)out_size; (void)ws_size;
}

// Round 6
// 99.869 us; speedup vs baseline: 1.7971x; 1.0937x over previous
//
#include <hip/hip_runtime.h>

#define S 2048
#define D 512
#define NH 32
#define DHD 16
#define DFF 1024
#define EPS 1e-5f
#define C1 0.36067376022224085f  // (1/sqrt(16)) * log2(e), folded into Q

typedef unsigned short u16;
typedef __attribute__((ext_vector_type(8))) short short8;
typedef __attribute__((ext_vector_type(4))) float f32x4;
typedef __attribute__((ext_vector_type(16))) float f32x16;
typedef __attribute__((ext_vector_type(4))) unsigned short us4;

#define GL_LDS(gsrc, ldst)                                                   \
  __builtin_amdgcn_global_load_lds(                                          \
      (const __attribute__((address_space(1))) unsigned int*)(gsrc),         \
      (__attribute__((address_space(3))) unsigned int*)(ldst), 16, 0, 0)

static __device__ __forceinline__ u16 f2bf(float f) {
  union { float f; unsigned int i; } c; c.f = f;
  unsigned int x = c.i;
  return (u16)((x + 0x7fffu + ((x >> 16) & 1u)) >> 16);
}
static __device__ __forceinline__ float bf2f(u16 v) {
  union { unsigned int i; float f; } c; c.i = ((unsigned int)v) << 16;
  return c.f;
}

static __device__ __forceinline__ float tmax16(const float* p) {
  float a0 = fmaxf(p[0], p[1]), a1 = fmaxf(p[2], p[3]);
  float a2 = fmaxf(p[4], p[5]), a3 = fmaxf(p[6], p[7]);
  float a4 = fmaxf(p[8], p[9]), a5 = fmaxf(p[10], p[11]);
  float a6 = fmaxf(p[12], p[13]), a7 = fmaxf(p[14], p[15]);
  float b0 = fmaxf(a0, a1), b1 = fmaxf(a2, a3);
  float b2 = fmaxf(a4, a5), b3 = fmaxf(a6, a7);
  return fmaxf(fmaxf(b0, b1), fmaxf(b2, b3));
}
static __device__ __forceinline__ float tsum16(const float* p) {
  float a0 = p[0] + p[1], a1 = p[2] + p[3], a2 = p[4] + p[5], a3 = p[6] + p[7];
  float a4 = p[8] + p[9], a5 = p[10] + p[11], a6 = p[12] + p[13], a7 = p[14] + p[15];
  float b0 = a0 + a1, b1 = a2 + a3, b2 = a4 + a5, b3 = a6 + a7;
  return (b0 + b1) + (b2 + b3);
}

static __device__ __forceinline__ void block_reduce2(float& a, float& b, float* sm, int t) {
#pragma unroll
  for (int m = 1; m <= 32; m <<= 1) {
    a += __shfl_xor(a, m);
    b += __shfl_xor(b, m);
  }
  int w = t >> 6;
  if ((t & 63) == 0) { sm[w] = a; sm[4 + w] = b; }
  __syncthreads();
  a = sm[0] + sm[1] + sm[2] + sm[3];
  b = sm[4] + sm[5] + sm[6] + sm[7];
  __syncthreads();
}

// ---------------- LN kernels ----------------
__global__ __launch_bounds__(256) void ln0_kernel(
    const float* __restrict__ x,
    const float* __restrict__ g0, const float* __restrict__ b0,
    const float* __restrict__ gq, const float* __restrict__ bq,
    const float* __restrict__ gk, const float* __restrict__ bk,
    const float* __restrict__ gv, const float* __restrict__ bv,
    float* __restrict__ xn, u16* __restrict__ qin, u16* __restrict__ kin,
    u16* __restrict__ vin) {
  __shared__ float red[8];
  int row = blockIdx.x, t = threadIdx.x;
  const float* xr = x + (size_t)row * D;
  float a0 = xr[t], a1 = xr[t + 256];
  float s = a0 + a1, ss = a0 * a0 + a1 * a1;
  block_reduce2(s, ss, red, t);
  float mean = s * (1.0f / D);
  float var = ss * (1.0f / D) - mean * mean;
  float rs = rsqrtf(var + EPS);
  float y0 = (a0 - mean) * rs * g0[t] + b0[t];
  float y1 = (a1 - mean) * rs * g0[t + 256] + b0[t + 256];
  size_t o = (size_t)row * D + t;
  xn[o] = y0;
  xn[o + 256] = y1;
  float s2 = y0 + y1, ss2 = y0 * y0 + y1 * y1;
  block_reduce2(s2, ss2, red, t);
  float m2 = s2 * (1.0f / D);
  float v2 = ss2 * (1.0f / D) - m2 * m2;
  float rs2 = rsqrtf(v2 + EPS);
  float c0 = (y0 - m2) * rs2, c1 = (y1 - m2) * rs2;
  qin[o] = f2bf(c0 * gq[t] + bq[t]);
  qin[o + 256] = f2bf(c1 * gq[t + 256] + bq[t + 256]);
  kin[o] = f2bf(c0 * gk[t] + bk[t]);
  kin[o + 256] = f2bf(c1 * gk[t + 256] + bk[t + 256]);
  vin[o] = f2bf(c0 * gv[t] + bv[t]);
  vin[o + 256] = f2bf(c1 * gv[t + 256] + bv[t + 256]);
}

__global__ __launch_bounds__(256) void ln2_kernel(
    const float* __restrict__ in, const float* __restrict__ g,
    const float* __restrict__ b, u16* __restrict__ out) {
  __shared__ float red[8];
  int row = blockIdx.x, t = threadIdx.x;
  const float* xr = in + (size_t)row * D;
  float a0 = xr[t], a1 = xr[t + 256];
  float s = a0 + a1, ss = a0 * a0 + a1 * a1;
  block_reduce2(s, ss, red, t);
  float mean = s * (1.0f / D);
  float var = ss * (1.0f / D) - mean * mean;
  float rs = rsqrtf(var + EPS);
  size_t o = (size_t)row * D + t;
  out[o] = f2bf((a0 - mean) * rs * g[t] + b[t]);
  out[o + 256] = f2bf((a1 - mean) * rs * g[t + 256] + b[t + 256]);
}

// ---------------- weight prep: fp32 W[K][N] -> bf16 fragment-tiled layout ----------------
// Frag layout (B-operand of mfma_32x32x16, N-major tiles):
//   I(n,k) = ((n>>5)*(K>>4) + (k>>4))*512 + ((n&31) + ((k>>3)&1)*32)*8 + (k&7)
__global__ void prep_weights(const float* __restrict__ Wq, const float* __restrict__ Wk,
                             const float* __restrict__ Wv, const float* __restrict__ Wo,
                             const float* __restrict__ W1, const float* __restrict__ W2,
                             u16* __restrict__ Fq, u16* __restrict__ Fk,
                             u16* __restrict__ Fv, u16* __restrict__ Fo,
                             u16* __restrict__ F1, u16* __restrict__ F2) {
  __shared__ float tile[32][33];
  int bz = blockIdx.x;
  const float* W;
  u16* F;
  int K, N, n0, k0;
  if (bz < 1024) {
    int wi = bz >> 8, tl = bz & 255;
    W = wi == 0 ? Wq : wi == 1 ? Wk : wi == 2 ? Wv : Wo;
    F = wi == 0 ? Fq : wi == 1 ? Fk : wi == 2 ? Fv : Fo;
    K = 512; N = 512;
    n0 = (tl & 15) * 32; k0 = (tl >> 4) * 32;
  } else if (bz < 1536) {
    int tl = bz - 1024;
    W = W1; F = F1; K = 512; N = 1024;
    n0 = (tl & 31) * 32; k0 = (tl >> 5) * 32;
  } else {
    int tl = bz - 1536;
    W = W2; F = F2; K = 1024; N = 512;
    n0 = (tl & 15) * 32; k0 = (tl >> 4) * 32;
  }
  int tx = threadIdx.x, ty = threadIdx.y;  // (32,8)
#pragma unroll
  for (int i = 0; i < 4; ++i)
    tile[ty + 8 * i][tx] = W[(size_t)(k0 + ty + 8 * i) * N + n0 + tx];
  __syncthreads();
  int k = k0 + tx;
  int kpart = ((k >> 3) & 1) * 32;
  int kj = k & 7;
#pragma unroll
  for (int i = 0; i < 4; ++i) {
    int n = n0 + ty + 8 * i;
    size_t I = (size_t)((n >> 5) * (K >> 4) + (k >> 4)) * 512 + ((n & 31) + kpart) * 8 + kj;
    F[I] = f2bf(tile[tx][ty + 8 * i]);
  }
}

// ---------------- GEMM: 64x64 block, BK=64, A via global_load_lds, B in regs ----------------
static __device__ __forceinline__ void stageA(const u16* __restrict__ A, int K,
                                              int m0, int kk, u16* As, int t) {
  int r = t >> 3, sl = t & 7;
  GL_LDS(A + (size_t)(m0 + r) * K + kk + ((sl ^ (r & 7)) * 8), As + t * 8);
  int r2 = r + 32;
  GL_LDS(A + (size_t)(m0 + r2) * K + kk + ((sl ^ (r2 & 7)) * 8), As + (t + 256) * 8);
}

static __device__ __forceinline__ void gemm64_acc(
    const u16* __restrict__ A, const u16* __restrict__ Wf, int K, int m0,
    int n32base, u16 (*As)[4096], f32x16& acc) {
  int t = threadIdx.x, w = t >> 6, lane = t & 63;
  int wm = w >> 1, wn = w & 1;
  int l31 = lane & 31, hi5 = lane >> 5;
  const u16* bp = Wf + (size_t)(n32base + wn) * (K >> 4) * 512 + lane * 8;
  stageA(A, K, m0, 0, As[0], t);
  short8 bcur[4], bnxt[4];
#pragma unroll
  for (int ks = 0; ks < 4; ++ks) bcur[ks] = *(const short8*)(bp + ks * 512);
  __syncthreads();
  int pb = 0;
  int arow = wm * 32 + l31;
  int abase = arow * 64;
  for (int kk = 0; kk < K; kk += 64) {
    if (kk + 64 < K) {
      stageA(A, K, m0, kk + 64, As[pb ^ 1], t);
      const u16* bp2 = bp + (size_t)(kk + 64) * 32;
#pragma unroll
      for (int ks = 0; ks < 4; ++ks) bnxt[ks] = *(const short8*)(bp2 + ks * 512);
    }
#pragma unroll
    for (int ks = 0; ks < 4; ++ks) {
      int slot = (ks * 2 + hi5) ^ (arow & 7);
      short8 af = *(const short8*)&As[pb][abase + slot * 8];
      acc = __builtin_amdgcn_mfma_f32_32x32x16_bf16(af, bcur[ks], acc, 0, 0, 0);
    }
    __syncthreads();
    pb ^= 1;
#pragma unroll
    for (int ks = 0; ks < 4; ++ks) bcur[ks] = bnxt[ks];
  }
}

template <bool RELU, bool RESID, bool OUTBF>
__global__ __launch_bounds__(256) void gemm_kernel(
    const u16* __restrict__ A, const u16* __restrict__ Wf,
    const float* __restrict__ bias, const float* __restrict__ resid,
    float* __restrict__ outf, u16* __restrict__ outb, int N, int K) {
  __shared__ u16 As[2][4096];
  int m0 = blockIdx.x * 64, n0 = blockIdx.y * 64;
  f32x16 acc = {};
  gemm64_acc(A, Wf, K, m0, blockIdx.y * 2, As, acc);
  int t = threadIdx.x, w = t >> 6, lane = t & 63;
  int wm = w >> 1, wn = w & 1;
  int l31 = lane & 31, hi5 = lane >> 5;
  int col = n0 + wn * 32 + l31;
  float bv = bias[col];
#pragma unroll
  for (int r = 0; r < 16; ++r) {
    int row = m0 + wm * 32 + (r & 3) + 8 * (r >> 2) + 4 * hi5;
    float v = acc[r] + bv;
    if (RELU) v = fmaxf(v, 0.0f);
    if (RESID) v += resid[(size_t)row * N + col];
    if (OUTBF)
      outb[(size_t)row * N + col] = f2bf(v);
    else
      outf[(size_t)row * N + col] = v;
  }
}

// QKV fused GEMM. z=0: Q row-major (scaled by C1). z=1: K fragment layout.
// z=2: V^T fragment layout (attention reads fragments directly from global).
__global__ __launch_bounds__(256) void gemm_qkv(
    const u16* __restrict__ a0, const u16* __restrict__ a1, const u16* __restrict__ a2,
    const u16* __restrict__ w0, const u16* __restrict__ w1, const u16* __restrict__ w2,
    const float* __restrict__ c0, const float* __restrict__ c1, const float* __restrict__ c2,
    u16* __restrict__ Qb, u16* __restrict__ KtG, u16* __restrict__ VtG) {
  __shared__ u16 As[2][4096];
  int z = blockIdx.z;
  const u16* A = z == 0 ? a0 : z == 1 ? a1 : a2;
  const u16* Wf = z == 0 ? w0 : z == 1 ? w1 : w2;
  const float* bias = z == 0 ? c0 : z == 1 ? c1 : c2;
  int m0 = blockIdx.x * 64, n0 = blockIdx.y * 64;
  f32x16 acc = {};
  gemm64_acc(A, Wf, D, m0, blockIdx.y * 2, As, acc);
  int t = threadIdx.x, w = t >> 6, lane = t & 63;
  int wm = w >> 1, wn = w & 1;
  int l31 = lane & 31, hi5 = lane >> 5;
  int col = n0 + wn * 32 + l31;
  float bv = bias[col];
  int h = col >> 4, d = col & 15;
#pragma unroll
  for (int r = 0; r < 16; ++r) {
    int row = m0 + wm * 32 + (r & 3) + 8 * (r >> 2) + 4 * hi5;
    float v = acc[r] + bv;
    if (z == 0) {
      Qb[(size_t)row * D + col] = f2bf(v * C1);
    } else if (z == 1) {
      int I = (((row >> 5) * 2 + (d >> 3)) * 32 + (row & 31)) * 8 + (d & 7);
      KtG[(size_t)h * 32768 + I] = f2bf(v);
    } else {
      int I = (((row >> 5) * 4 + ((row >> 3) & 3)) * 16 + d) * 8 + (row & 7);
      VtG[(size_t)h * 32768 + I] = f2bf(v);
    }
  }
}

// ---------------- causal flash attention, split-KV, barrier-free ----------------
__global__ __launch_bounds__(128) void attn_kernel(const u16* __restrict__ Qb,
                                                   const u16* __restrict__ KtG,
                                                   const u16* __restrict__ VtG,
                                                   u16* __restrict__ ctx,
                                                   u16* __restrict__ part) {
  __shared__ u16 Pl[2][2048];

  const int t = threadIdx.x, w = t >> 6, lane = t & 63;
  const int h = blockIdx.y;
  const int f = 143 - blockIdx.x;  // longest chunks dispatched first
  int g = (int)((sqrtf((float)(1 + 2 * f)) - 1.0f) * 0.5f);
  while (2 * (g + 1) * (g + 2) <= f) ++g;
  while (2 * g * (g + 1) > f) --g;
  const int fg = f - 2 * g * (g + 1);
  const int qt = 4 * g + fg / (g + 1);
  const int c = fg - (fg / (g + 1)) * (g + 1);
  const int t0 = 4 * c;
  const int t1 = (4 * c + 3 < qt) ? 4 * c + 3 : qt;

  const int q0w = qt * 64 + w * 32;
  const int lq = lane & 31, hi = lane >> 5;
  const int l16 = lane & 15, g4 = lane >> 4;

  short8 qf = *(const short8*)(Qb + (size_t)(q0w + lq) * D + h * DHD + hi * 8);
  const u16* kp = KtG + (size_t)h * 32768 + (size_t)t0 * 1024 + hi * 256 + lq * 8;
  const u16* vp = VtG + (size_t)h * 32768 + (size_t)t0 * 1024 + g4 * 128 + l16 * 8;

  f32x4 acc[2] = {};
  float Mrun = -1e30f, Lrun = 0.0f;

  short8 kf0 = *(const short8*)kp;
  short8 kf1 = *(const short8*)(kp + 512);
  short8 vf0 = *(const short8*)vp;
  short8 vf1 = *(const short8*)(vp + 512);

  u16* Pw = &Pl[w][0];
  const int pwr = (lq >> 4) * 1024 + (lq & 15) * 8 + 4 * hi;  // P write base
  const int prd = g4 * 128 + l16 * 8;                          // P read base

  for (int tt = t0; tt <= t1; ++tt) {
    const int kv0 = tt * 64;
    const bool v1 = (kv0 + 32) <= (q0w + 31);
    f32x16 z = {};
    f32x16 st0 = __builtin_amdgcn_mfma_f32_32x32x16_bf16(kf0, qf, z, 0, 0, 0);
    f32x16 st1 = z;
    if (v1) st1 = __builtin_amdgcn_mfma_f32_32x32x16_bf16(kf1, qf, z, 0, 0, 0);

    short8 nk0, nk1, nv0, nv1;
    const bool more = (tt < t1);
    if (more) {  // issue next-tile loads early; they hide under softmax
      kp += 1024; vp += 1024;
      nk0 = *(const short8*)kp;
      nk1 = *(const short8*)(kp + 512);
      nv0 = *(const short8*)vp;
      nv1 = *(const short8*)(vp + 512);
    }

    // ---- mask (cheap per-lane threshold) ----
    float p0[16], p1[16];
    const int thr0 = q0w + lq - kv0 - 4 * hi;
    if (kv0 + 31 > q0w) {
#pragma unroll
      for (int r = 0; r < 16; ++r) {
        const int rc = (r & 3) + 8 * (r >> 2);
        p0[r] = (rc > thr0) ? -1e30f : st0[r];
      }
    } else {
#pragma unroll
      for (int r = 0; r < 16; ++r) p0[r] = st0[r];
    }
    if (v1) {
      const int thr1 = thr0 - 32;
      if (kv0 + 63 > q0w) {
#pragma unroll
        for (int r = 0; r < 16; ++r) {
          const int rc = (r & 3) + 8 * (r >> 2);
          p1[r] = (rc > thr1) ? -1e30f : st1[r];
        }
      } else {
#pragma unroll
        for (int r = 0; r < 16; ++r) p1[r] = st1[r];
      }
    }

    // ---- online softmax with T13 defer-rescale ----
    float mx = tmax16(p0);
    if (v1) mx = fmaxf(mx, tmax16(p1));
    mx = fmaxf(mx, __shfl_xor(mx, 32));
    if (!__all(mx - Mrun <= 8.0f)) {
      float Mnew = fmaxf(Mrun, mx);
      float corr = exp2f(Mrun - Mnew);
      Lrun *= corr;
      Mrun = Mnew;
#pragma unroll
      for (int sq = 0; sq < 2; ++sq)
#pragma unroll
        for (int r = 0; r < 4; ++r) {
          float cc = __shfl(corr, sq * 16 + g4 * 4 + r);
          acc[sq][r] *= cc;
        }
    }
#pragma unroll
    for (int r = 0; r < 16; ++r) p0[r] = exp2f(p0[r] - Mrun);
    float sum = tsum16(p0);
    if (v1) {
#pragma unroll
      for (int r = 0; r < 16; ++r) p1[r] = exp2f(p1[r] - Mrun);
      sum += tsum16(p1);
    }
    sum += __shfl_xor(sum, 32);
    Lrun += sum;

    // ---- pack P (cvt_pk) into swizzled per-wave LDS ----
#pragma unroll
    for (int k = 0; k < 4; ++k) {
      unsigned int w0, w1;
      asm("v_cvt_pk_bf16_f32 %0, %1, %2" : "=v"(w0) : "v"(p0[4 * k]), "v"(p0[4 * k + 1]));
      asm("v_cvt_pk_bf16_f32 %0, %1, %2" : "=v"(w1) : "v"(p0[4 * k + 2]), "v"(p0[4 * k + 3]));
      uint2 pv; pv.x = w0; pv.y = w1;
      *(uint2*)&Pw[(pwr + k * 128) ^ (k << 4)] = pv;
    }
    if (v1) {
#pragma unroll
      for (int k = 0; k < 4; ++k) {
        unsigned int w0, w1;
        asm("v_cvt_pk_bf16_f32 %0, %1, %2" : "=v"(w0) : "v"(p1[4 * k]), "v"(p1[4 * k + 1]));
        asm("v_cvt_pk_bf16_f32 %0, %1, %2" : "=v"(w1) : "v"(p1[4 * k + 2]), "v"(p1[4 * k + 3]));
        uint2 pv; pv.x = w0; pv.y = w1;
        *(uint2*)&Pw[(pwr + 512 + k * 128) ^ (k << 4)] = pv;
      }
    }

    // ---- PV (V fragments live in registers) ----
#pragma unroll
    for (int sx = 0; sx < 2; ++sx) {
      if (sx == 0 || v1) {
        short8 vf = sx ? vf1 : vf0;
#pragma unroll
        for (int sq = 0; sq < 2; ++sq) {
          short8 pf = *(const short8*)&Pw[(sq * 1024 + sx * 512 + prd) ^ (g4 << 4)];
          acc[sq] = __builtin_amdgcn_mfma_f32_16x16x32_bf16(pf, vf, acc[sq], 0, 0, 0);
        }
      }
    }

    if (more) { kf0 = nk0; kf1 = nk1; vf0 = nv0; vf1 = nv1; }
  }

  if (g == 0) {  // single chunk: direct output
#pragma unroll
    for (int sq = 0; sq < 2; ++sq)
#pragma unroll
      for (int r = 0; r < 4; ++r) {
        int qlr = sq * 16 + g4 * 4 + r;
        float lv = __shfl(Lrun, qlr);
        ctx[(size_t)(q0w + qlr) * D + h * DHD + l16] = f2bf(acc[sq][r] / lv);
      }
  } else {
    // partial row: 20 u16 = [m f32][l f32][16 x bf16 O]
    const int pslot = 2 * g * (g + 1) + (qt - 4 * g) * (g + 1) - 4 + c;
    u16* ps = part + ((size_t)(h * 140 + pslot)) * 1280;
#pragma unroll
    for (int sq = 0; sq < 2; ++sq)
#pragma unroll
      for (int r = 0; r < 4; ++r) {
        int qlocal = w * 32 + sq * 16 + g4 * 4 + r;
        ps[qlocal * 20 + 4 + l16] = f2bf(acc[sq][r]);
      }
    if (hi == 0) {
      int ql = w * 32 + lq;
      *(float*)(ps + ql * 20) = Mrun;
      *(float*)(ps + ql * 20 + 2) = Lrun;
    }
  }
}

// ---------------- merge split-KV partials (qt >= 4) ----------------
__global__ __launch_bounds__(64) void attn_merge(const u16* __restrict__ part,
                                                 u16* __restrict__ ctx) {
  int qt = 4 + blockIdx.x, h = blockIdx.y, tq = threadIdx.x;
  int g = qt >> 2, nc = g + 1;
  int base = 2 * g * (g + 1) + (qt - 4 * g) * (g + 1) - 4;
  const u16* bp = part + ((size_t)(h * 140 + base)) * 1280 + tq * 20;
  float M = -1e30f;
  for (int c = 0; c < nc; ++c) M = fmaxf(M, *(const float*)(bp + (size_t)c * 1280));
  float L = 0.0f;
  float o[16];
#pragma unroll
  for (int d = 0; d < 16; ++d) o[d] = 0.0f;
  for (int c = 0; c < nc; ++c) {
    const u16* pr = bp + (size_t)c * 1280;
    float m = *(const float*)pr;
    float l = *(const float*)(pr + 2);
    float sc = exp2f(m - M);
    L += l * sc;
#pragma unroll
    for (int k = 0; k < 4; ++k) {
      us4 ov = *(const us4*)(pr + 4 + 4 * k);
#pragma unroll
      for (int j = 0; j < 4; ++j) o[4 * k + j] += bf2f(ov[j]) * sc;
    }
  }
  float inv = 1.0f / L;
  int q = qt * 64 + tq;
  u16* op = ctx + (size_t)q * D + h * DHD;
#pragma unroll
  for (int k = 0; k < 4; ++k) {
    us4 pk;
#pragma unroll
    for (int j = 0; j < 4; ++j) pk[j] = f2bf(o[4 * k + j] * inv);
    *(us4*)(op + 4 * k) = pk;
  }
}

// ---------------- launcher ----------------
extern "C" void kernel_launch(void* const* d_in, const int* in_sizes, int n_in,
                              void* d_out, int out_size, void* d_ws, size_t ws_size,
                              hipStream_t stream) {
  const float* x = (const float*)d_in[0];
  const float* ln0_g = (const float*)d_in[1];
  const float* ln0_b = (const float*)d_in[2];
  const float* lnq_g = (const float*)d_in[3];
  const float* lnq_b = (const float*)d_in[4];
  const float* lnk_g = (const float*)d_in[5];
  const float* lnk_b = (const float*)d_in[6];
  const float* lnv_g = (const float*)d_in[7];
  const float* lnv_b = (const float*)d_in[8];
  const float* Wq = (const float*)d_in[9];
  const float* bq = (const float*)d_in[10];
  const float* Wk = (const float*)d_in[11];
  const float* bk = (const float*)d_in[12];
  const float* Wv = (const float*)d_in[13];
  const float* bv = (const float*)d_in[14];
  const float* Wo = (const float*)d_in[15];
  const float* bo = (const float*)d_in[16];
  const float* lnf_g = (const float*)d_in[17];
  const float* lnf_b = (const float*)d_in[18];
  const float* W1 = (const float*)d_in[19];
  const float* b1 = (const float*)d_in[20];
  const float* W2 = (const float*)d_in[21];
  const float* b2 = (const float*)d_in[22];

  char* wsp = (char*)d_ws;
  size_t off = 0;
  auto alloc = [&](size_t bytes) -> void* {
    void* p = wsp + off;
    off += (bytes + 255) & ~(size_t)255;
    return p;
  };
  // ---- fixed region (live across attention) ----
  float* xn = (float*)alloc((size_t)S * D * 4);
  u16* Qb = (u16*)alloc((size_t)S * D * 2);
  u16* ctx = (u16*)alloc((size_t)S * D * 2);
  u16* KtG = (u16*)alloc((size_t)S * D * 2);
  u16* VtG = (u16*)alloc((size_t)S * D * 2);
  u16* WfQ = (u16*)alloc((size_t)D * D * 2);
  u16* WfK = (u16*)alloc((size_t)D * D * 2);
  u16* WfV = (u16*)alloc((size_t)D * D * 2);
  u16* WfO = (u16*)alloc((size_t)D * D * 2);
  u16* Wf1 = (u16*)alloc((size_t)D * DFF * 2);
  u16* Wf2 = (u16*)alloc((size_t)DFF * D * 2);
  // ---- multiplexed region B (phases don't overlap in stream order) ----
  char* regB = (char*)alloc((size_t)15 * 1024 * 1024);
  u16* qin = (u16*)regB;                                  // phase 1
  u16* kin = (u16*)(regB + (size_t)S * D * 2);
  u16* vin = (u16*)(regB + (size_t)S * D * 4);
  u16* part = (u16*)regB;                                 // phase 2 (11.47MB)
  float* outb = (float*)regB;                             // phase 3
  u16* lnf = (u16*)(regB + (size_t)S * D * 4);
  u16* hbuf = (u16*)(regB + (size_t)S * D * 6);

  prep_weights<<<dim3(2048), dim3(32, 8), 0, stream>>>(Wq, Wk, Wv, Wo, W1, W2,
                                                       WfQ, WfK, WfV, WfO, Wf1, Wf2);

  ln0_kernel<<<S, 256, 0, stream>>>(x, ln0_g, ln0_b, lnq_g, lnq_b, lnk_g, lnk_b,
                                    lnv_g, lnv_b, xn, qin, kin, vin);

  gemm_qkv<<<dim3(S / 64, D / 64, 3), 256, 0, stream>>>(
      qin, kin, vin, WfQ, WfK, WfV, bq, bk, bv, Qb, KtG, VtG);

  attn_kernel<<<dim3(144, NH), 128, 0, stream>>>(Qb, KtG, VtG, ctx, part);

  attn_merge<<<dim3(28, NH), 64, 0, stream>>>(part, ctx);

  gemm_kernel<false, true, false><<<dim3(S / 64, D / 64), 256, 0, stream>>>(
      ctx, WfO, bo, xn, outb, nullptr, D, D);

  ln2_kernel<<<S, 256, 0, stream>>>(outb, lnf_g, lnf_b, lnf);

  gemm_kernel<true, false, true><<<dim3(S / 64, DFF / 64), 256, 0, stream>>>(
      lnf, Wf1, b1, nullptr, nullptr, hbuf, DFF, D);

  gemm_kernel<true, true, false><<<dim3(S / 64, D / 64), 256, 0, stream>>>(
      hbuf, Wf2, b2, outb, (float*)d_out, nullptr, D, DFF);

  (void)in_sizes; (void)n_in; (void)out_size; (void)ws_size;
}

// Round 7
// 94.304 us; speedup vs baseline: 1.9031x; 1.0590x over previous
//
#include <hip/hip_runtime.h>

#define S 2048
#define D 512
#define NH 32
#define DHD 16
#define DFF 1024
#define EPS 1e-5f
#define C1 0.36067376022224085f  // (1/sqrt(16)) * log2(e), folded into Q

typedef unsigned short u16;
typedef __attribute__((ext_vector_type(8))) short short8;
typedef __attribute__((ext_vector_type(4))) float f32x4;
typedef __attribute__((ext_vector_type(16))) float f32x16;
typedef __attribute__((ext_vector_type(4))) unsigned short us4;

#define GL_LDS(gsrc, ldst)                                                   \
  __builtin_amdgcn_global_load_lds(                                          \
      (const __attribute__((address_space(1))) unsigned int*)(gsrc),         \
      (__attribute__((address_space(3))) unsigned int*)(ldst), 16, 0, 0)

static __device__ __forceinline__ u16 f2bf(float f) {
  union { float f; unsigned int i; } c; c.f = f;
  unsigned int x = c.i;
  return (u16)((x + 0x7fffu + ((x >> 16) & 1u)) >> 16);
}
static __device__ __forceinline__ float bf2f(u16 v) {
  union { unsigned int i; float f; } c; c.i = ((unsigned int)v) << 16;
  return c.f;
}

static __device__ __forceinline__ float tsum16(const float* p) {
  float a0 = p[0] + p[1], a1 = p[2] + p[3], a2 = p[4] + p[5], a3 = p[6] + p[7];
  float a4 = p[8] + p[9], a5 = p[10] + p[11], a6 = p[12] + p[13], a7 = p[14] + p[15];
  float b0 = a0 + a1, b1 = a2 + a3, b2 = a4 + a5, b3 = a6 + a7;
  return (b0 + b1) + (b2 + b3);
}

// ---------------- LN kernels: one wave per row, no barriers ----------------
__global__ __launch_bounds__(256) void ln0_kernel(
    const float* __restrict__ x,
    const float* __restrict__ g0, const float* __restrict__ b0,
    const float* __restrict__ gq, const float* __restrict__ bq,
    const float* __restrict__ gk, const float* __restrict__ bk,
    const float* __restrict__ gv, const float* __restrict__ bv,
    float* __restrict__ xn, u16* __restrict__ qin, u16* __restrict__ kin,
    u16* __restrict__ vin) {
  int w = threadIdx.x >> 6, lane = threadIdx.x & 63;
  int row = blockIdx.x * 4 + w;
  int c = lane * 8;
  const float* xr = x + (size_t)row * D + c;
  float4 xa = *(const float4*)xr;
  float4 xb = *(const float4*)(xr + 4);
  float a[8] = {xa.x, xa.y, xa.z, xa.w, xb.x, xb.y, xb.z, xb.w};
  float s = 0.0f, ss = 0.0f;
#pragma unroll
  for (int i = 0; i < 8; ++i) { s += a[i]; ss += a[i] * a[i]; }
#pragma unroll
  for (int m = 1; m <= 32; m <<= 1) { s += __shfl_xor(s, m); ss += __shfl_xor(ss, m); }
  float mean = s * (1.0f / D);
  float rs = rsqrtf(ss * (1.0f / D) - mean * mean + EPS);
  float4 ga = *(const float4*)(g0 + c), gb = *(const float4*)(g0 + c + 4);
  float4 ba = *(const float4*)(b0 + c), bb = *(const float4*)(b0 + c + 4);
  float gg[8] = {ga.x, ga.y, ga.z, ga.w, gb.x, gb.y, gb.z, gb.w};
  float bbv[8] = {ba.x, ba.y, ba.z, ba.w, bb.x, bb.y, bb.z, bb.w};
  float y[8];
  float s2 = 0.0f, ss2 = 0.0f;
#pragma unroll
  for (int i = 0; i < 8; ++i) {
    y[i] = (a[i] - mean) * rs * gg[i] + bbv[i];
    s2 += y[i]; ss2 += y[i] * y[i];
  }
  float* xo = xn + (size_t)row * D + c;
  *(float4*)xo = {y[0], y[1], y[2], y[3]};
  *(float4*)(xo + 4) = {y[4], y[5], y[6], y[7]};
#pragma unroll
  for (int m = 1; m <= 32; m <<= 1) { s2 += __shfl_xor(s2, m); ss2 += __shfl_xor(ss2, m); }
  float m2 = s2 * (1.0f / D);
  float rs2 = rsqrtf(ss2 * (1.0f / D) - m2 * m2 + EPS);
  float cn[8];
#pragma unroll
  for (int i = 0; i < 8; ++i) cn[i] = (y[i] - m2) * rs2;
  size_t o = (size_t)row * D + c;
#pragma unroll
  for (int br = 0; br < 3; ++br) {
    const float* gp = br == 0 ? gq : br == 1 ? gk : gv;
    const float* bp = br == 0 ? bq : br == 1 ? bk : bv;
    u16* op = br == 0 ? qin : br == 1 ? kin : vin;
    float4 g1 = *(const float4*)(gp + c), g2 = *(const float4*)(gp + c + 4);
    float4 b1 = *(const float4*)(bp + c), b2 = *(const float4*)(bp + c + 4);
    float gv2[8] = {g1.x, g1.y, g1.z, g1.w, g2.x, g2.y, g2.z, g2.w};
    float bv2[8] = {b1.x, b1.y, b1.z, b1.w, b2.x, b2.y, b2.z, b2.w};
    us4 o1, o2;
#pragma unroll
    for (int i = 0; i < 4; ++i) o1[i] = f2bf(cn[i] * gv2[i] + bv2[i]);
#pragma unroll
    for (int i = 0; i < 4; ++i) o2[i] = f2bf(cn[4 + i] * gv2[4 + i] + bv2[4 + i]);
    *(us4*)(op + o) = o1;
    *(us4*)(op + o + 4) = o2;
  }
}

__global__ __launch_bounds__(256) void ln2_kernel(
    const float* __restrict__ in, const float* __restrict__ g,
    const float* __restrict__ b, u16* __restrict__ out) {
  int w = threadIdx.x >> 6, lane = threadIdx.x & 63;
  int row = blockIdx.x * 4 + w;
  int c = lane * 8;
  const float* xr = in + (size_t)row * D + c;
  float4 xa = *(const float4*)xr;
  float4 xb = *(const float4*)(xr + 4);
  float a[8] = {xa.x, xa.y, xa.z, xa.w, xb.x, xb.y, xb.z, xb.w};
  float s = 0.0f, ss = 0.0f;
#pragma unroll
  for (int i = 0; i < 8; ++i) { s += a[i]; ss += a[i] * a[i]; }
#pragma unroll
  for (int m = 1; m <= 32; m <<= 1) { s += __shfl_xor(s, m); ss += __shfl_xor(ss, m); }
  float mean = s * (1.0f / D);
  float rs = rsqrtf(ss * (1.0f / D) - mean * mean + EPS);
  float4 ga = *(const float4*)(g + c), gb = *(const float4*)(g + c + 4);
  float4 ba = *(const float4*)(b + c), bb = *(const float4*)(b + c + 4);
  float gg[8] = {ga.x, ga.y, ga.z, ga.w, gb.x, gb.y, gb.z, gb.w};
  float bbv[8] = {ba.x, ba.y, ba.z, ba.w, bb.x, bb.y, bb.z, bb.w};
  us4 o1, o2;
#pragma unroll
  for (int i = 0; i < 4; ++i) o1[i] = f2bf((a[i] - mean) * rs * gg[i] + bbv[i]);
#pragma unroll
  for (int i = 0; i < 4; ++i) o2[i] = f2bf((a[4 + i] - mean) * rs * gg[4 + i] + bbv[4 + i]);
  *(us4*)(out + (size_t)row * D + c) = o1;
  *(us4*)(out + (size_t)row * D + c + 4) = o2;
}

// ---------------- weight prep: fp32 W[K][N] -> bf16 fragment-tiled layout ----------------
__global__ void prep_weights(const float* __restrict__ Wq, const float* __restrict__ Wk,
                             const float* __restrict__ Wv, const float* __restrict__ Wo,
                             const float* __restrict__ W1, const float* __restrict__ W2,
                             u16* __restrict__ Fq, u16* __restrict__ Fk,
                             u16* __restrict__ Fv, u16* __restrict__ Fo,
                             u16* __restrict__ F1, u16* __restrict__ F2) {
  __shared__ float tile[32][33];
  int bz = blockIdx.x;
  const float* W;
  u16* F;
  int K, N, n0, k0;
  if (bz < 1024) {
    int wi = bz >> 8, tl = bz & 255;
    W = wi == 0 ? Wq : wi == 1 ? Wk : wi == 2 ? Wv : Wo;
    F = wi == 0 ? Fq : wi == 1 ? Fk : wi == 2 ? Fv : Fo;
    K = 512; N = 512;
    n0 = (tl & 15) * 32; k0 = (tl >> 4) * 32;
  } else if (bz < 1536) {
    int tl = bz - 1024;
    W = W1; F = F1; K = 512; N = 1024;
    n0 = (tl & 31) * 32; k0 = (tl >> 5) * 32;
  } else {
    int tl = bz - 1536;
    W = W2; F = F2; K = 1024; N = 512;
    n0 = (tl & 15) * 32; k0 = (tl >> 4) * 32;
  }
  int tx = threadIdx.x, ty = threadIdx.y;  // (32,8)
#pragma unroll
  for (int i = 0; i < 4; ++i)
    tile[ty + 8 * i][tx] = W[(size_t)(k0 + ty + 8 * i) * N + n0 + tx];
  __syncthreads();
  int k = k0 + tx;
  int kpart = ((k >> 3) & 1) * 32;
  int kj = k & 7;
#pragma unroll
  for (int i = 0; i < 4; ++i) {
    int n = n0 + ty + 8 * i;
    size_t I = (size_t)((n >> 5) * (K >> 4) + (k >> 4)) * 512 + ((n & 31) + kpart) * 8 + kj;
    F[I] = f2bf(tile[tx][ty + 8 * i]);
  }
}

// ---------------- GEMM: 64x64 block, BK=64, A via global_load_lds, B in regs ----------------
static __device__ __forceinline__ void stageA(const u16* __restrict__ A, int K,
                                              int m0, int kk, u16* As, int t) {
  int r = t >> 3, sl = t & 7;
  GL_LDS(A + (size_t)(m0 + r) * K + kk + ((sl ^ (r & 7)) * 8), As + t * 8);
  int r2 = r + 32;
  GL_LDS(A + (size_t)(m0 + r2) * K + kk + ((sl ^ (r2 & 7)) * 8), As + (t + 256) * 8);
}

static __device__ __forceinline__ void gemm64_acc(
    const u16* __restrict__ A, const u16* __restrict__ Wf, int K, int m0,
    int n32base, u16 (*As)[4096], f32x16& acc) {
  int t = threadIdx.x, w = t >> 6, lane = t & 63;
  int wm = w >> 1, wn = w & 1;
  int l31 = lane & 31, hi5 = lane >> 5;
  const u16* bp = Wf + (size_t)(n32base + wn) * (K >> 4) * 512 + lane * 8;
  stageA(A, K, m0, 0, As[0], t);
  short8 bcur[4], bnxt[4];
#pragma unroll
  for (int ks = 0; ks < 4; ++ks) bcur[ks] = *(const short8*)(bp + ks * 512);
  __syncthreads();
  int pb = 0;
  int arow = wm * 32 + l31;
  int abase = arow * 64;
  for (int kk = 0; kk < K; kk += 64) {
    if (kk + 64 < K) {
      stageA(A, K, m0, kk + 64, As[pb ^ 1], t);
      const u16* bp2 = bp + (size_t)(kk + 64) * 32;
#pragma unroll
      for (int ks = 0; ks < 4; ++ks) bnxt[ks] = *(const short8*)(bp2 + ks * 512);
    }
#pragma unroll
    for (int ks = 0; ks < 4; ++ks) {
      int slot = (ks * 2 + hi5) ^ (arow & 7);
      short8 af = *(const short8*)&As[pb][abase + slot * 8];
      acc = __builtin_amdgcn_mfma_f32_32x32x16_bf16(af, bcur[ks], acc, 0, 0, 0);
    }
    __syncthreads();
    pb ^= 1;
#pragma unroll
    for (int ks = 0; ks < 4; ++ks) bcur[ks] = bnxt[ks];
  }
}

template <bool RELU, bool RESID, bool OUTBF>
__global__ __launch_bounds__(256) void gemm_kernel(
    const u16* __restrict__ A, const u16* __restrict__ Wf,
    const float* __restrict__ bias, const float* __restrict__ resid,
    float* __restrict__ outf, u16* __restrict__ outb, int N, int K) {
  __shared__ u16 As[2][4096];
  int m0 = blockIdx.x * 64, n0 = blockIdx.y * 64;
  f32x16 acc = {};
  gemm64_acc(A, Wf, K, m0, blockIdx.y * 2, As, acc);
  int t = threadIdx.x, w = t >> 6, lane = t & 63;
  int wm = w >> 1, wn = w & 1;
  int l31 = lane & 31, hi5 = lane >> 5;
  int col = n0 + wn * 32 + l31;
  float bv = bias[col];
#pragma unroll
  for (int r = 0; r < 16; ++r) {
    int row = m0 + wm * 32 + (r & 3) + 8 * (r >> 2) + 4 * hi5;
    float v = acc[r] + bv;
    if (RELU) v = fmaxf(v, 0.0f);
    if (RESID) v += resid[(size_t)row * N + col];
    if (OUTBF)
      outb[(size_t)row * N + col] = f2bf(v);
    else
      outf[(size_t)row * N + col] = v;
  }
}

// QKV fused GEMM. z=0: Q row-major (scaled by C1). z=1: K fragment layout.
// z=2: V^T fragment layout (attention reads fragments directly from global).
__global__ __launch_bounds__(256) void gemm_qkv(
    const u16* __restrict__ a0, const u16* __restrict__ a1, const u16* __restrict__ a2,
    const u16* __restrict__ w0, const u16* __restrict__ w1, const u16* __restrict__ w2,
    const float* __restrict__ c0, const float* __restrict__ c1, const float* __restrict__ c2,
    u16* __restrict__ Qb, u16* __restrict__ KtG, u16* __restrict__ VtG) {
  __shared__ u16 As[2][4096];
  int z = blockIdx.z;
  const u16* A = z == 0 ? a0 : z == 1 ? a1 : a2;
  const u16* Wf = z == 0 ? w0 : z == 1 ? w1 : w2;
  const float* bias = z == 0 ? c0 : z == 1 ? c1 : c2;
  int m0 = blockIdx.x * 64, n0 = blockIdx.y * 64;
  f32x16 acc = {};
  gemm64_acc(A, Wf, D, m0, blockIdx.y * 2, As, acc);
  int t = threadIdx.x, w = t >> 6, lane = t & 63;
  int wm = w >> 1, wn = w & 1;
  int l31 = lane & 31, hi5 = lane >> 5;
  int col = n0 + wn * 32 + l31;
  float bv = bias[col];
  int h = col >> 4, d = col & 15;
  if (z == 2) {  // vectorized: 4 consecutive rows are contiguous in V layout
#pragma unroll
    for (int rg = 0; rg < 4; ++rg) {
      int row = m0 + wm * 32 + 8 * rg + 4 * hi5;
      us4 pk;
#pragma unroll
      for (int j = 0; j < 4; ++j) pk[j] = f2bf(acc[rg * 4 + j] + bv);
      int I = (((row >> 5) * 4 + ((row >> 3) & 3)) * 16 + d) * 8 + (row & 7);
      *(us4*)(VtG + (size_t)h * 32768 + I) = pk;
    }
  } else {
#pragma unroll
    for (int r = 0; r < 16; ++r) {
      int row = m0 + wm * 32 + (r & 3) + 8 * (r >> 2) + 4 * hi5;
      float v = acc[r] + bv;
      if (z == 0) {
        Qb[(size_t)row * D + col] = f2bf(v * C1);
      } else {
        int I = (((row >> 5) * 2 + (d >> 3)) * 32 + (row & 31)) * 8 + (d & 7);
        KtG[(size_t)h * 32768 + I] = f2bf(v);
      }
    }
  }
}

// ---------------- causal flash attention, split-KV, no-max softmax ----------------
// Softmax without running-max: scores are LN-bounded (|st| << 127), so
// exp2(st) cannot overflow (clamped at 125 as insurance); softmax is
// shift-invariant so the result is exact. Partials reduce to (O, L) sums.
__global__ __launch_bounds__(128) void attn_kernel(const u16* __restrict__ Qb,
                                                   const u16* __restrict__ KtG,
                                                   const u16* __restrict__ VtG,
                                                   u16* __restrict__ ctx,
                                                   u16* __restrict__ part) {
  __shared__ u16 Pl[2][2048];

  const int t = threadIdx.x, w = t >> 6, lane = t & 63;
  const int h = blockIdx.y;
  const int f = 143 - blockIdx.x;  // longest chunks dispatched first
  int g = (int)((sqrtf((float)(1 + 2 * f)) - 1.0f) * 0.5f);
  while (2 * (g + 1) * (g + 2) <= f) ++g;
  while (2 * g * (g + 1) > f) --g;
  const int fg = f - 2 * g * (g + 1);
  const int qt = 4 * g + fg / (g + 1);
  const int c = fg - (fg / (g + 1)) * (g + 1);
  const int t0 = 4 * c;
  const int t1 = (4 * c + 3 < qt) ? 4 * c + 3 : qt;

  const int q0w = qt * 64 + w * 32;
  const int lq = lane & 31, hi = lane >> 5;
  const int l16 = lane & 15, g4 = lane >> 4;

  short8 qf = *(const short8*)(Qb + (size_t)(q0w + lq) * D + h * DHD + hi * 8);
  const u16* kp = KtG + (size_t)h * 32768 + (size_t)t0 * 1024 + hi * 256 + lq * 8;
  const u16* vp = VtG + (size_t)h * 32768 + (size_t)t0 * 1024 + g4 * 128 + l16 * 8;

  f32x4 acc[2] = {};
  float Lrun = 0.0f;

  short8 kf0 = *(const short8*)kp;
  short8 kf1 = *(const short8*)(kp + 512);
  short8 vf0 = *(const short8*)vp;
  short8 vf1 = *(const short8*)(vp + 512);

  u16* Pw = &Pl[w][0];
  const int pwr = (lq >> 4) * 1024 + (lq & 15) * 8 + 4 * hi;  // P write base
  const int prd = g4 * 128 + l16 * 8;                          // P read base

  for (int tt = t0; tt <= t1; ++tt) {
    const int kv0 = tt * 64;
    const bool v1 = (kv0 + 32) <= (q0w + 31);
    f32x16 z = {};
    f32x16 st0 = __builtin_amdgcn_mfma_f32_32x32x16_bf16(kf0, qf, z, 0, 0, 0);
    f32x16 st1 = z;
    if (v1) st1 = __builtin_amdgcn_mfma_f32_32x32x16_bf16(kf1, qf, z, 0, 0, 0);

    short8 nk0, nk1, nv0, nv1;
    const bool more = (tt < t1);
    if (more) {  // issue next-tile loads early; they hide under softmax
      kp += 1024; vp += 1024;
      nk0 = *(const short8*)kp;
      nk1 = *(const short8*)(kp + 512);
      nv0 = *(const short8*)vp;
      nv1 = *(const short8*)(vp + 512);
    }

    // ---- mask (diag tiles) + exp2, no max subtraction ----
    float p0[16], p1[16];
    const int thr0 = q0w + lq - kv0 - 4 * hi;
    if (kv0 + 31 > q0w) {
#pragma unroll
      for (int r = 0; r < 16; ++r) {
        const int rc = (r & 3) + 8 * (r >> 2);
        p0[r] = (rc > thr0) ? -1e30f : st0[r];
      }
    } else {
#pragma unroll
      for (int r = 0; r < 16; ++r) p0[r] = st0[r];
    }
#pragma unroll
    for (int r = 0; r < 16; ++r) p0[r] = exp2f(fminf(p0[r], 125.0f));
    float sum = tsum16(p0);
    if (v1) {
      const int thr1 = thr0 - 32;
      if (kv0 + 63 > q0w) {
#pragma unroll
        for (int r = 0; r < 16; ++r) {
          const int rc = (r & 3) + 8 * (r >> 2);
          p1[r] = (rc > thr1) ? -1e30f : st1[r];
        }
      } else {
#pragma unroll
        for (int r = 0; r < 16; ++r) p1[r] = st1[r];
      }
#pragma unroll
      for (int r = 0; r < 16; ++r) p1[r] = exp2f(fminf(p1[r], 125.0f));
      sum += tsum16(p1);
    }
    sum += __shfl_xor(sum, 32);
    Lrun += sum;

    // ---- pack P (cvt_pk) into swizzled per-wave LDS ----
#pragma unroll
    for (int k = 0; k < 4; ++k) {
      unsigned int w0, w1;
      asm("v_cvt_pk_bf16_f32 %0, %1, %2" : "=v"(w0) : "v"(p0[4 * k]), "v"(p0[4 * k + 1]));
      asm("v_cvt_pk_bf16_f32 %0, %1, %2" : "=v"(w1) : "v"(p0[4 * k + 2]), "v"(p0[4 * k + 3]));
      uint2 pv; pv.x = w0; pv.y = w1;
      *(uint2*)&Pw[(pwr + k * 128) ^ (k << 4)] = pv;
    }
    if (v1) {
#pragma unroll
      for (int k = 0; k < 4; ++k) {
        unsigned int w0, w1;
        asm("v_cvt_pk_bf16_f32 %0, %1, %2" : "=v"(w0) : "v"(p1[4 * k]), "v"(p1[4 * k + 1]));
        asm("v_cvt_pk_bf16_f32 %0, %1, %2" : "=v"(w1) : "v"(p1[4 * k + 2]), "v"(p1[4 * k + 3]));
        uint2 pv; pv.x = w0; pv.y = w1;
        *(uint2*)&Pw[(pwr + 512 + k * 128) ^ (k << 4)] = pv;
      }
    }

    // ---- PV (V fragments live in registers) ----
#pragma unroll
    for (int sx = 0; sx < 2; ++sx) {
      if (sx == 0 || v1) {
        short8 vf = sx ? vf1 : vf0;
#pragma unroll
        for (int sq = 0; sq < 2; ++sq) {
          short8 pf = *(const short8*)&Pw[(sq * 1024 + sx * 512 + prd) ^ (g4 << 4)];
          acc[sq] = __builtin_amdgcn_mfma_f32_16x16x32_bf16(pf, vf, acc[sq], 0, 0, 0);
        }
      }
    }

    if (more) { kf0 = nk0; kf1 = nk1; vf0 = nv0; vf1 = nv1; }
  }

  if (g == 0) {  // single chunk: direct output
#pragma unroll
    for (int sq = 0; sq < 2; ++sq)
#pragma unroll
      for (int r = 0; r < 4; ++r) {
        int qlr = sq * 16 + g4 * 4 + r;
        float lv = __shfl(Lrun, qlr);
        float inv = __builtin_amdgcn_rcpf(lv);
        ctx[(size_t)(q0w + qlr) * D + h * DHD + l16] = f2bf(acc[sq][r] * inv);
      }
  } else {
    // partial row: 20 u16 = [L f32][16 x bf16 O][pad]
    const int pslot = 2 * g * (g + 1) + (qt - 4 * g) * (g + 1) - 4 + c;
    u16* ps = part + ((size_t)(h * 140 + pslot)) * 1280;
#pragma unroll
    for (int sq = 0; sq < 2; ++sq)
#pragma unroll
      for (int r = 0; r < 4; ++r) {
        int qlocal = w * 32 + sq * 16 + g4 * 4 + r;
        ps[qlocal * 20 + 2 + l16] = f2bf(acc[sq][r]);
      }
    if (hi == 0) {
      *(float*)(ps + (w * 32 + lq) * 20) = Lrun;
    }
  }
}

// ---------------- merge split-KV partials (qt >= 4): pure (O,L) sums ----------------
__global__ __launch_bounds__(64) void attn_merge(const u16* __restrict__ part,
                                                 u16* __restrict__ ctx) {
  int qt = 4 + blockIdx.x, h = blockIdx.y, tq = threadIdx.x;
  int g = qt >> 2, nc = g + 1;
  int base = 2 * g * (g + 1) + (qt - 4 * g) * (g + 1) - 4;
  const u16* bp = part + ((size_t)(h * 140 + base)) * 1280 + tq * 20;
  float L = 0.0f;
  float o[16];
#pragma unroll
  for (int d = 0; d < 16; ++d) o[d] = 0.0f;
  for (int c = 0; c < nc; ++c) {
    const u16* pr = bp + (size_t)c * 1280;
    L += *(const float*)pr;
#pragma unroll
    for (int k = 0; k < 4; ++k) {
      us4 ov = *(const us4*)(pr + 2 + 4 * k);
#pragma unroll
      for (int j = 0; j < 4; ++j) o[4 * k + j] += bf2f(ov[j]);
    }
  }
  float inv = 1.0f / L;
  int q = qt * 64 + tq;
  u16* op = ctx + (size_t)q * D + h * DHD;
#pragma unroll
  for (int k = 0; k < 4; ++k) {
    us4 pk;
#pragma unroll
    for (int j = 0; j < 4; ++j) pk[j] = f2bf(o[4 * k + j] * inv);
    *(us4*)(op + 4 * k) = pk;
  }
}

// ---------------- launcher ----------------
extern "C" void kernel_launch(void* const* d_in, const int* in_sizes, int n_in,
                              void* d_out, int out_size, void* d_ws, size_t ws_size,
                              hipStream_t stream) {
  const float* x = (const float*)d_in[0];
  const float* ln0_g = (const float*)d_in[1];
  const float* ln0_b = (const float*)d_in[2];
  const float* lnq_g = (const float*)d_in[3];
  const float* lnq_b = (const float*)d_in[4];
  const float* lnk_g = (const float*)d_in[5];
  const float* lnk_b = (const float*)d_in[6];
  const float* lnv_g = (const float*)d_in[7];
  const float* lnv_b = (const float*)d_in[8];
  const float* Wq = (const float*)d_in[9];
  const float* bq = (const float*)d_in[10];
  const float* Wk = (const float*)d_in[11];
  const float* bk = (const float*)d_in[12];
  const float* Wv = (const float*)d_in[13];
  const float* bv = (const float*)d_in[14];
  const float* Wo = (const float*)d_in[15];
  const float* bo = (const float*)d_in[16];
  const float* lnf_g = (const float*)d_in[17];
  const float* lnf_b = (const float*)d_in[18];
  const float* W1 = (const float*)d_in[19];
  const float* b1 = (const float*)d_in[20];
  const float* W2 = (const float*)d_in[21];
  const float* b2 = (const float*)d_in[22];

  char* wsp = (char*)d_ws;
  size_t off = 0;
  auto alloc = [&](size_t bytes) -> void* {
    void* p = wsp + off;
    off += (bytes + 255) & ~(size_t)255;
    return p;
  };
  // ---- fixed region (live across attention) ----
  float* xn = (float*)alloc((size_t)S * D * 4);
  u16* Qb = (u16*)alloc((size_t)S * D * 2);
  u16* ctx = (u16*)alloc((size_t)S * D * 2);
  u16* KtG = (u16*)alloc((size_t)S * D * 2);
  u16* VtG = (u16*)alloc((size_t)S * D * 2);
  u16* WfQ = (u16*)alloc((size_t)D * D * 2);
  u16* WfK = (u16*)alloc((size_t)D * D * 2);
  u16* WfV = (u16*)alloc((size_t)D * D * 2);
  u16* WfO = (u16*)alloc((size_t)D * D * 2);
  u16* Wf1 = (u16*)alloc((size_t)D * DFF * 2);
  u16* Wf2 = (u16*)alloc((size_t)DFF * D * 2);
  // ---- multiplexed region B (phases don't overlap in stream order) ----
  char* regB = (char*)alloc((size_t)15 * 1024 * 1024);
  u16* qin = (u16*)regB;                                  // phase 1
  u16* kin = (u16*)(regB + (size_t)S * D * 2);
  u16* vin = (u16*)(regB + (size_t)S * D * 4);
  u16* part = (u16*)regB;                                 // phase 2 (11.47MB)
  float* outb = (float*)regB;                             // phase 3
  u16* lnf = (u16*)(regB + (size_t)S * D * 4);
  u16* hbuf = (u16*)(regB + (size_t)S * D * 6);

  prep_weights<<<dim3(2048), dim3(32, 8), 0, stream>>>(Wq, Wk, Wv, Wo, W1, W2,
                                                       WfQ, WfK, WfV, WfO, Wf1, Wf2);

  ln0_kernel<<<S / 4, 256, 0, stream>>>(x, ln0_g, ln0_b, lnq_g, lnq_b, lnk_g, lnk_b,
                                        lnv_g, lnv_b, xn, qin, kin, vin);

  gemm_qkv<<<dim3(S / 64, D / 64, 3), 256, 0, stream>>>(
      qin, kin, vin, WfQ, WfK, WfV, bq, bk, bv, Qb, KtG, VtG);

  attn_kernel<<<dim3(144, NH), 128, 0, stream>>>(Qb, KtG, VtG, ctx, part);

  attn_merge<<<dim3(28, NH), 64, 0, stream>>>(part, ctx);

  gemm_kernel<false, true, false><<<dim3(S / 64, D / 64), 256, 0, stream>>>(
      ctx, WfO, bo, xn, outb, nullptr, D, D);

  ln2_kernel<<<S / 4, 256, 0, stream>>>(outb, lnf_g, lnf_b, lnf);

  gemm_kernel<true, false, true><<<dim3(S / 64, DFF / 64), 256, 0, stream>>>(
      lnf, Wf1, b1, nullptr, nullptr, hbuf, DFF, D);

  gemm_kernel<true, true, false><<<dim3(S / 64, D / 64), 256, 0, stream>>>(
      hbuf, Wf2, b2, outb, (float*)d_out, nullptr, D, DFF);

  (void)in_sizes; (void)n_in; (void)out_size; (void)ws_size;
}